// Round 1
// baseline (3915.184 us; speedup 1.0000x reference)
//
#include <hip/hip_runtime.h>

#define L_SEQ 2048
#define DMODEL 1024
#define DINNER 2048
#define DSTATE 16
#define DTRANK 64
#define DBC_LD 96
#define ISIZE 4096

typedef __bf16 bf16x8 __attribute__((ext_vector_type(8)));
typedef float f32x4 __attribute__((ext_vector_type(4)));

// ---------------------------------------------------------------- GEMM NT
// C[r][c] = sum_k A[r][k] * W[c][k]   (A: M x K row-major lda, W: N x K row-major ldb)
// EPI: 0 = store, 1 = softplus(acc + aux[c]), 2 = C[flip(r)] += acc, 3 = C = aux[r*ldc+c] + acc
template<int EPI, bool FLIP>
__global__ __launch_bounds__(256) void gemm_nt(
    const float* __restrict__ A, const float* __restrict__ W,
    float* __restrict__ C, const float* __restrict__ aux,
    int M, int N, int K, int lda, int ldb, int ldc)
{
    __shared__ __bf16 lsA[64 * 48];
    __shared__ __bf16 lsB[64 * 48];
    const int tid  = threadIdx.x;
    const int lane = tid & 63;
    const int wave = tid >> 6;
    const int wm = (wave >> 1) * 32, wn = (wave & 1) * 32;
    const int m0 = blockIdx.x * 64, n0 = blockIdx.y * 64;
    const int sr = tid >> 2, sq = tid & 3;       // staging: row 0..63, k-quarter 0..3
    const int lr = lane & 15, lk = (lane >> 4) * 8;

    f32x4 acc[2][2] = {};

    for (int k0 = 0; k0 < K; k0 += 32) {
        __syncthreads();
        {   // stage A tile (64 x 32), f32 -> bf16
            const float* src = A + (size_t)(m0 + sr) * lda + k0 + sq * 8;
            float4 v0 = *(const float4*)src;
            float4 v1 = *(const float4*)(src + 4);
            bf16x8 o;
            o[0]=(__bf16)v0.x; o[1]=(__bf16)v0.y; o[2]=(__bf16)v0.z; o[3]=(__bf16)v0.w;
            o[4]=(__bf16)v1.x; o[5]=(__bf16)v1.y; o[6]=(__bf16)v1.z; o[7]=(__bf16)v1.w;
            *(bf16x8*)&lsA[sr * 48 + sq * 8] = o;
        }
        {   // stage B tile (64 x 32) from W rows, guard n < N
            bf16x8 o = {};
            if (n0 + sr < N) {
                const float* src = W + (size_t)(n0 + sr) * ldb + k0 + sq * 8;
                float4 v0 = *(const float4*)src;
                float4 v1 = *(const float4*)(src + 4);
                o[0]=(__bf16)v0.x; o[1]=(__bf16)v0.y; o[2]=(__bf16)v0.z; o[3]=(__bf16)v0.w;
                o[4]=(__bf16)v1.x; o[5]=(__bf16)v1.y; o[6]=(__bf16)v1.z; o[7]=(__bf16)v1.w;
            }
            *(bf16x8*)&lsB[sr * 48 + sq * 8] = o;
        }
        __syncthreads();
        bf16x8 a0 = *(const bf16x8*)&lsA[(wm + lr)      * 48 + lk];
        bf16x8 a1 = *(const bf16x8*)&lsA[(wm + 16 + lr) * 48 + lk];
        bf16x8 b0 = *(const bf16x8*)&lsB[(wn + lr)      * 48 + lk];
        bf16x8 b1 = *(const bf16x8*)&lsB[(wn + 16 + lr) * 48 + lk];
        acc[0][0] = __builtin_amdgcn_mfma_f32_16x16x32_bf16(a0, b0, acc[0][0], 0, 0, 0);
        acc[0][1] = __builtin_amdgcn_mfma_f32_16x16x32_bf16(a0, b1, acc[0][1], 0, 0, 0);
        acc[1][0] = __builtin_amdgcn_mfma_f32_16x16x32_bf16(a1, b0, acc[1][0], 0, 0, 0);
        acc[1][1] = __builtin_amdgcn_mfma_f32_16x16x32_bf16(a1, b1, acc[1][1], 0, 0, 0);
    }

    const int cr = (lane >> 4) * 4;
    const int cc = lane & 15;
    #pragma unroll
    for (int mi = 0; mi < 2; ++mi)
    #pragma unroll
    for (int ni = 0; ni < 2; ++ni) {
        const int c = n0 + wn + ni * 16 + cc;
        if (c >= N) continue;
        #pragma unroll
        for (int g = 0; g < 4; ++g) {
            const int r = m0 + wm + mi * 16 + cr + g;
            float v = acc[mi][ni][g];
            if (EPI == 0) {
                C[(size_t)r * ldc + c] = v;
            } else if (EPI == 1) {
                float xv = v + aux[c];
                C[(size_t)r * ldc + c] = (xv > 20.f) ? xv : log1pf(__expf(xv));
            } else if (EPI == 2) {
                const int rr = FLIP ? (M - 1 - r) : r;
                C[(size_t)rr * ldc + c] += v;
            } else {
                C[(size_t)r * ldc + c] = aux[(size_t)r * ldc + c] + v;
            }
        }
    }
}

// ---------------------------------------------------------------- rmsnorm1 (+mask, + flipped copy)
__global__ __launch_bounds__(256) void rmsnorm_mask_kernel(
    const float* __restrict__ x, const float* __restrict__ w, const float* __restrict__ mask,
    float* __restrict__ h, float* __restrict__ hrev)
{
    __shared__ float sred[4];
    const int row = blockIdx.x, t = threadIdx.x;
    float4 v = ((const float4*)(x + (size_t)row * DMODEL))[t];
    float ss = v.x*v.x + v.y*v.y + v.z*v.z + v.w*v.w;
    #pragma unroll
    for (int m = 1; m < 64; m <<= 1) ss += __shfl_xor(ss, m);
    if ((t & 63) == 0) sred[t >> 6] = ss;
    __syncthreads();
    ss = sred[0] + sred[1] + sred[2] + sred[3];
    const float scale = rsqrtf(ss * (1.f / DMODEL) + 1e-6f) * mask[row];
    float4 wv = ((const float4*)w)[t];
    float4 o;
    o.x = v.x * wv.x * scale; o.y = v.y * wv.y * scale;
    o.z = v.z * wv.z * scale; o.w = v.w * wv.w * scale;
    ((float4*)(h    + (size_t)row * DMODEL))[t] = o;
    ((float4*)(hrev + (size_t)(L_SEQ - 1 - row) * DMODEL))[t] = o;
}

// ---------------------------------------------------------------- causal depthwise conv (k=4) + silu
__global__ __launch_bounds__(256) void conv_silu_kernel(
    const float* __restrict__ xz, const float* __restrict__ w,
    const float* __restrict__ b, float* __restrict__ xc)
{
    const int idx = blockIdx.x * 256 + threadIdx.x;   // over L*DINNER
    const int d = idx & (DINNER - 1);
    const int t = idx >> 11;
    float acc = b[d];
    const float4 wv = *(const float4*)(w + d * 4);
    const float wj[4] = {wv.x, wv.y, wv.z, wv.w};
    #pragma unroll
    for (int j = 0; j < 4; ++j) {
        const int tt = t - 3 + j;
        if (tt >= 0) acc += wj[j] * xz[(size_t)tt * ISIZE + d];
    }
    xc[(size_t)idx] = acc / (1.f + __expf(-acc));
}

// ---------------------------------------------------------------- selective scan (+ Dp skip + silu(z) gate)
__global__ __launch_bounds__(256) void scan_kernel(
    const float* __restrict__ u, const float* __restrict__ dt,
    const float* __restrict__ dbc, const float* __restrict__ A_log,
    const float* __restrict__ Dp, const float* __restrict__ z, float* __restrict__ out)
{
    const int tid = threadIdx.x;
    const int n = tid & 15, dl = tid >> 4;
    const int d = blockIdx.x * 16 + dl;
    const float A  = -__expf(A_log[d * DSTATE + n]);
    const float Dv = Dp[d];
    float hs = 0.f;
    for (int t = 0; t < L_SEQ; ++t) {
        const float dtv = dt[(size_t)t * DINNER + d];
        const float uv  = u[(size_t)t * DINNER + d];
        const float Bv  = dbc[t * DBC_LD + DTRANK + n];
        const float Cv  = dbc[t * DBC_LD + DTRANK + DSTATE + n];
        const float dA  = __expf(dtv * A);
        hs = dA * hs + (dtv * uv) * Bv;
        float py = hs * Cv;
        py += __shfl_xor(py, 1);
        py += __shfl_xor(py, 2);
        py += __shfl_xor(py, 4);
        py += __shfl_xor(py, 8);
        if (n == 0) {
            const float zv = z[(size_t)t * ISIZE + d];
            const float yv = py + uv * Dv;
            out[(size_t)t * DINNER + d] = yv * (zv / (1.f + __expf(-zv)));
        }
    }
}

// ---------------------------------------------------------------- x2 = x + rmsnorm(ysum)*mw ; h2 = rmsnorm(x2)*w2
__global__ __launch_bounds__(256) void addnorm2_kernel(
    const float* __restrict__ x0, const float* __restrict__ ys,
    const float* __restrict__ mw, const float* __restrict__ w2,
    float* __restrict__ x2, float* __restrict__ h2)
{
    __shared__ float sred[8];
    const int row = blockIdx.x, t = threadIdx.x;
    float4 yv = ((const float4*)(ys + (size_t)row * DMODEL))[t];
    float ss = yv.x*yv.x + yv.y*yv.y + yv.z*yv.z + yv.w*yv.w;
    #pragma unroll
    for (int m = 1; m < 64; m <<= 1) ss += __shfl_xor(ss, m);
    if ((t & 63) == 0) sred[t >> 6] = ss;
    __syncthreads();
    const float s1 = sred[0] + sred[1] + sred[2] + sred[3];
    const float sc1 = rsqrtf(s1 * (1.f / DMODEL) + 1e-6f);
    float4 xv = ((const float4*)(x0 + (size_t)row * DMODEL))[t];
    float4 mv = ((const float4*)mw)[t];
    float4 o;
    o.x = xv.x + mv.x * yv.x * sc1; o.y = xv.y + mv.y * yv.y * sc1;
    o.z = xv.z + mv.z * yv.z * sc1; o.w = xv.w + mv.w * yv.w * sc1;
    ((float4*)(x2 + (size_t)row * DMODEL))[t] = o;
    float s2 = o.x*o.x + o.y*o.y + o.z*o.z + o.w*o.w;
    #pragma unroll
    for (int m = 1; m < 64; m <<= 1) s2 += __shfl_xor(s2, m);
    if ((t & 63) == 0) sred[4 + (t >> 6)] = s2;
    __syncthreads();
    const float st = sred[4] + sred[5] + sred[6] + sred[7];
    const float sc2 = rsqrtf(st * (1.f / DMODEL) + 1e-6f);
    float4 wv = ((const float4*)w2)[t];
    float4 o2;
    o2.x = wv.x * o.x * sc2; o2.y = wv.y * o.y * sc2;
    o2.z = wv.z * o.z * sc2; o2.w = wv.w * o.w * sc2;
    ((float4*)(h2 + (size_t)row * DMODEL))[t] = o2;
}

// ---------------------------------------------------------------- m = silu(g) * u
__global__ __launch_bounds__(256) void silu_mul_kernel(
    const float* __restrict__ g, const float* __restrict__ u, float* __restrict__ m)
{
    const size_t i = (size_t)blockIdx.x * 256 + threadIdx.x;
    const float gv = g[i], uv = u[i];
    m[i] = gv / (1.f + __expf(-gv)) * uv;
}

// ---------------------------------------------------------------- launch
extern "C" void kernel_launch(void* const* d_in, const int* in_sizes, int n_in,
                              void* d_out, int out_size, void* d_ws, size_t ws_size,
                              hipStream_t stream)
{
    const float* x       = (const float*)d_in[0];
    const float* mask    = (const float*)d_in[1];
    const float* mnorm_w = (const float*)d_in[2];
    const float* ln1_w   = (const float*)d_in[3];
    const float* ln2_w   = (const float*)d_in[4];
    const float* gate_w  = (const float*)d_in[5];
    const float* up_w    = (const float*)d_in[6];
    const float* down_w  = (const float*)d_in[7];
    const float* in_w[2]    = {(const float*)d_in[8],  (const float*)d_in[17]};
    const float* conv_w[2]  = {(const float*)d_in[9],  (const float*)d_in[18]};
    const float* conv_b[2]  = {(const float*)d_in[10], (const float*)d_in[19]};
    const float* xproj_w[2] = {(const float*)d_in[11], (const float*)d_in[20]};
    const float* dt_w[2]    = {(const float*)d_in[12], (const float*)d_in[21]};
    const float* dt_b[2]    = {(const float*)d_in[13], (const float*)d_in[22]};
    const float* A_log[2]   = {(const float*)d_in[14], (const float*)d_in[23]};
    const float* Dp[2]      = {(const float*)d_in[15], (const float*)d_in[24]};
    const float* out_w[2]   = {(const float*)d_in[16], (const float*)d_in[25]};

    float* ws = (float*)d_ws;
    const size_t S1 = (size_t)L_SEQ * DMODEL;       // 2M floats
    float* h     = ws;                // L x 1024
    float* hrev  = ws + S1;           // L x 1024
    float* ysum  = ws + 2 * S1;       // L x 1024
    float* x2    = ws + 3 * S1;       // L x 1024
    float* bufA  = ws + 4 * S1;       // L x 4096 : xz / mlp-gate
    float* xc    = ws + 8 * S1;       // L x 2048
    float* dtb   = ws + 10 * S1;      // L x 2048
    float* ygate = ws + 12 * S1;      // L x 2048
    float* dbc   = ws + 14 * S1;      // L x 96
    float* ubuf  = ws + 8 * S1;       // MLP up   (reuses xc+dtb)
    float* mbuf  = ws + 12 * S1;      // MLP mid  (reuses ygate+dbc)

    rmsnorm_mask_kernel<<<L_SEQ, 256, 0, stream>>>(x, ln1_w, mask, h, hrev);

    for (int dir = 0; dir < 2; ++dir) {
        const float* hd = dir ? hrev : h;
        // xz = h @ in_w^T            (2048 x 4096, K=1024)
        gemm_nt<0, false><<<dim3(32, 64), 256, 0, stream>>>(
            hd, in_w[dir], bufA, nullptr, 2048, 4096, 1024, 1024, 1024, 4096);
        // xc = silu(causal_conv(xi))
        conv_silu_kernel<<<(L_SEQ * DINNER) / 256, 256, 0, stream>>>(
            bufA, conv_w[dir], conv_b[dir], xc);
        // dbc = xc @ xproj^T         (2048 x 96, K=2048)
        gemm_nt<0, false><<<dim3(32, 2), 256, 0, stream>>>(
            xc, xproj_w[dir], dbc, nullptr, 2048, 96, 2048, 2048, 2048, 96);
        // dt = softplus(dt_raw @ dt_w^T + dt_b)   (2048 x 2048, K=64)
        gemm_nt<1, false><<<dim3(32, 32), 256, 0, stream>>>(
            dbc, dt_w[dir], dtb, dt_b[dir], 2048, 2048, 64, 96, 64, 2048);
        // selective scan + Dp skip + silu(z) gating
        scan_kernel<<<DINNER / 16, 256, 0, stream>>>(
            xc, dtb, dbc, A_log[dir], Dp[dir], bufA + DINNER, ygate);
        // out-proj (fwd: store; bwd: accumulate with row flip)
        if (dir == 0)
            gemm_nt<0, false><<<dim3(32, 16), 256, 0, stream>>>(
                ygate, out_w[0], ysum, nullptr, 2048, 1024, 2048, 2048, 2048, 1024);
        else
            gemm_nt<2, true><<<dim3(32, 16), 256, 0, stream>>>(
                ygate, out_w[1], ysum, nullptr, 2048, 1024, 2048, 2048, 2048, 1024);
    }

    // x2 = x + rmsnorm(ysum)*mnorm_w ; h2 = rmsnorm(x2)*ln2_w  (h2 stored in h)
    addnorm2_kernel<<<L_SEQ, 256, 0, stream>>>(x, ysum, mnorm_w, ln2_w, x2, h);

    // MLP
    gemm_nt<0, false><<<dim3(32, 64), 256, 0, stream>>>(
        h, gate_w, bufA, nullptr, 2048, 4096, 1024, 1024, 1024, 4096);
    gemm_nt<0, false><<<dim3(32, 64), 256, 0, stream>>>(
        h, up_w, ubuf, nullptr, 2048, 4096, 1024, 1024, 1024, 4096);
    silu_mul_kernel<<<(L_SEQ * ISIZE) / 256, 256, 0, stream>>>(bufA, ubuf, mbuf);
    gemm_nt<3, false><<<dim3(32, 16), 256, 0, stream>>>(
        mbuf, down_w, (float*)d_out, x2, 2048, 1024, 4096, 4096, 4096, 1024);
}

// Round 2
// 818.726 us; speedup vs baseline: 4.7820x; 4.7820x over previous
//
#include <hip/hip_runtime.h>

#define L_SEQ 2048
#define DMODEL 1024
#define DINNER 2048
#define DSTATE 16
#define DTRANK 64
#define DBC_LD 96
#define ISIZE 4096
#define NC 64   // scan chunks
#define TC 32   // timesteps per chunk

typedef __bf16 bf16x8 __attribute__((ext_vector_type(8)));
typedef float f32x4 __attribute__((ext_vector_type(4)));

// P/S chunk-summary buffers live in the dead xi-half of bufA (cols 0..2047 of
// the L x 4096 xz buffer, which is consumed by conv before the scan runs).
// Linear index i in [0, 2M) -> row i>>11, col i&2047 -> offset row*4096 + col.
__device__ __forceinline__ float ps_ld(const float* b, int i) {
    return b[((size_t)(i >> 11) << 12) + (i & 2047)];
}
__device__ __forceinline__ void ps_st(float* b, int i, float v) {
    b[((size_t)(i >> 11) << 12) + (i & 2047)] = v;
}

// ---------------------------------------------------------------- GEMM NT
// C[r][c] = sum_k A[r][k] * W[c][k]   (A: M x K row-major lda, W: N x K row-major ldb)
// EPI: 0 = store, 1 = softplus(acc + aux[c]), 2 = C[flip(r)] += acc, 3 = C = aux[r*ldc+c] + acc
template<int EPI, bool FLIP>
__global__ __launch_bounds__(256) void gemm_nt(
    const float* __restrict__ A, const float* __restrict__ W,
    float* __restrict__ C, const float* __restrict__ aux,
    int M, int N, int K, int lda, int ldb, int ldc)
{
    __shared__ __bf16 lsA[64 * 48];
    __shared__ __bf16 lsB[64 * 48];
    const int tid  = threadIdx.x;
    const int lane = tid & 63;
    const int wave = tid >> 6;
    const int wm = (wave >> 1) * 32, wn = (wave & 1) * 32;
    const int m0 = blockIdx.x * 64, n0 = blockIdx.y * 64;
    const int sr = tid >> 2, sq = tid & 3;       // staging: row 0..63, k-quarter 0..3
    const int lr = lane & 15, lk = (lane >> 4) * 8;

    f32x4 acc[2][2] = {};

    for (int k0 = 0; k0 < K; k0 += 32) {
        __syncthreads();
        {   // stage A tile (64 x 32), f32 -> bf16
            const float* src = A + (size_t)(m0 + sr) * lda + k0 + sq * 8;
            float4 v0 = *(const float4*)src;
            float4 v1 = *(const float4*)(src + 4);
            bf16x8 o;
            o[0]=(__bf16)v0.x; o[1]=(__bf16)v0.y; o[2]=(__bf16)v0.z; o[3]=(__bf16)v0.w;
            o[4]=(__bf16)v1.x; o[5]=(__bf16)v1.y; o[6]=(__bf16)v1.z; o[7]=(__bf16)v1.w;
            *(bf16x8*)&lsA[sr * 48 + sq * 8] = o;
        }
        {   // stage B tile (64 x 32) from W rows, guard n < N
            bf16x8 o = {};
            if (n0 + sr < N) {
                const float* src = W + (size_t)(n0 + sr) * ldb + k0 + sq * 8;
                float4 v0 = *(const float4*)src;
                float4 v1 = *(const float4*)(src + 4);
                o[0]=(__bf16)v0.x; o[1]=(__bf16)v0.y; o[2]=(__bf16)v0.z; o[3]=(__bf16)v0.w;
                o[4]=(__bf16)v1.x; o[5]=(__bf16)v1.y; o[6]=(__bf16)v1.z; o[7]=(__bf16)v1.w;
            }
            *(bf16x8*)&lsB[sr * 48 + sq * 8] = o;
        }
        __syncthreads();
        bf16x8 a0 = *(const bf16x8*)&lsA[(wm + lr)      * 48 + lk];
        bf16x8 a1 = *(const bf16x8*)&lsA[(wm + 16 + lr) * 48 + lk];
        bf16x8 b0 = *(const bf16x8*)&lsB[(wn + lr)      * 48 + lk];
        bf16x8 b1 = *(const bf16x8*)&lsB[(wn + 16 + lr) * 48 + lk];
        acc[0][0] = __builtin_amdgcn_mfma_f32_16x16x32_bf16(a0, b0, acc[0][0], 0, 0, 0);
        acc[0][1] = __builtin_amdgcn_mfma_f32_16x16x32_bf16(a0, b1, acc[0][1], 0, 0, 0);
        acc[1][0] = __builtin_amdgcn_mfma_f32_16x16x32_bf16(a1, b0, acc[1][0], 0, 0, 0);
        acc[1][1] = __builtin_amdgcn_mfma_f32_16x16x32_bf16(a1, b1, acc[1][1], 0, 0, 0);
    }

    const int cr = (lane >> 4) * 4;
    const int cc = lane & 15;
    #pragma unroll
    for (int mi = 0; mi < 2; ++mi)
    #pragma unroll
    for (int ni = 0; ni < 2; ++ni) {
        const int c = n0 + wn + ni * 16 + cc;
        if (c >= N) continue;
        #pragma unroll
        for (int g = 0; g < 4; ++g) {
            const int r = m0 + wm + mi * 16 + cr + g;
            float v = acc[mi][ni][g];
            if (EPI == 0) {
                C[(size_t)r * ldc + c] = v;
            } else if (EPI == 1) {
                float xv = v + aux[c];
                C[(size_t)r * ldc + c] = (xv > 20.f) ? xv : log1pf(__expf(xv));
            } else if (EPI == 2) {
                const int rr = FLIP ? (M - 1 - r) : r;
                C[(size_t)rr * ldc + c] += v;
            } else {
                C[(size_t)r * ldc + c] = aux[(size_t)r * ldc + c] + v;
            }
        }
    }
}

// ---------------------------------------------------------------- rmsnorm1 (+mask, + flipped copy)
__global__ __launch_bounds__(256) void rmsnorm_mask_kernel(
    const float* __restrict__ x, const float* __restrict__ w, const float* __restrict__ mask,
    float* __restrict__ h, float* __restrict__ hrev)
{
    __shared__ float sred[4];
    const int row = blockIdx.x, t = threadIdx.x;
    float4 v = ((const float4*)(x + (size_t)row * DMODEL))[t];
    float ss = v.x*v.x + v.y*v.y + v.z*v.z + v.w*v.w;
    #pragma unroll
    for (int m = 1; m < 64; m <<= 1) ss += __shfl_xor(ss, m);
    if ((t & 63) == 0) sred[t >> 6] = ss;
    __syncthreads();
    ss = sred[0] + sred[1] + sred[2] + sred[3];
    const float scale = rsqrtf(ss * (1.f / DMODEL) + 1e-6f) * mask[row];
    float4 wv = ((const float4*)w)[t];
    float4 o;
    o.x = v.x * wv.x * scale; o.y = v.y * wv.y * scale;
    o.z = v.z * wv.z * scale; o.w = v.w * wv.w * scale;
    ((float4*)(h    + (size_t)row * DMODEL))[t] = o;
    ((float4*)(hrev + (size_t)(L_SEQ - 1 - row) * DMODEL))[t] = o;
}

// ---------------------------------------------------------------- causal depthwise conv (k=4) + silu
__global__ __launch_bounds__(256) void conv_silu_kernel(
    const float* __restrict__ xz, const float* __restrict__ w,
    const float* __restrict__ b, float* __restrict__ xc)
{
    const int idx = blockIdx.x * 256 + threadIdx.x;   // over L*DINNER
    const int d = idx & (DINNER - 1);
    const int t = idx >> 11;
    float acc = b[d];
    const float4 wv = *(const float4*)(w + d * 4);
    const float wj[4] = {wv.x, wv.y, wv.z, wv.w};
    #pragma unroll
    for (int j = 0; j < 4; ++j) {
        const int tt = t - 3 + j;
        if (tt >= 0) acc += wj[j] * xz[(size_t)tt * ISIZE + d];
    }
    xc[(size_t)idx] = acc / (1.f + __expf(-acc));
}

// ---------------------------------------------------------------- scan phase 1: per-chunk summaries
// P[c][d*16+n] = prod_t exp(dt*A), S[c][d*16+n] = local scan end (h with h_init=0)
__global__ __launch_bounds__(256) void scan_p1(
    const float* __restrict__ u, const float* __restrict__ dt,
    const float* __restrict__ dbc, const float* __restrict__ A_log,
    float* __restrict__ Pb, float* __restrict__ Sb)
{
    __shared__ float sdt[TC * 16], su[TC * 16], sB[TC * 16];
    const int tid = threadIdx.x;
    const int n = tid & 15, dl = tid >> 4;
    const int c = blockIdx.x, dg = blockIdx.y;
    const int d = dg * 16 + dl;
    const int t0 = c * TC;
    for (int i = tid; i < TC * 16; i += 256) {
        const int tt = i >> 4, dd = i & 15;
        sdt[i] = dt[(size_t)(t0 + tt) * DINNER + dg * 16 + dd];
        su[i]  = u [(size_t)(t0 + tt) * DINNER + dg * 16 + dd];
        sB[i]  = dbc[(t0 + tt) * DBC_LD + DTRANK + dd];
    }
    __syncthreads();
    const float A = -__expf(A_log[d * DSTATE + n]);
    float hs = 0.f, Pa = 1.f;
    #pragma unroll
    for (int t = 0; t < TC; ++t) {
        const float dtv = sdt[t * 16 + dl];
        const float a = __expf(dtv * A);
        hs = a * hs + (dtv * su[t * 16 + dl]) * sB[t * 16 + n];
        Pa *= a;
    }
    const int idn = d * DSTATE + n;
    ps_st(Pb, c * 32768 + idn, Pa);
    ps_st(Sb, c * 32768 + idn, hs);
}

// ---------------------------------------------------------------- scan phase 2: combine chunk states
__global__ __launch_bounds__(256) void scan_mid(
    const float* __restrict__ Pb, const float* __restrict__ Sb, float* __restrict__ Hinit)
{
    const int i = blockIdx.x * 256 + threadIdx.x;   // (d,n) index, 0..32767
    float H = 0.f;
    for (int c = 0; c < NC; ++c) {
        Hinit[(size_t)c * 32768 + i] = H;
        H = ps_ld(Pb, c * 32768 + i) * H + ps_ld(Sb, c * 32768 + i);
    }
}

// ---------------------------------------------------------------- scan phase 3: recompute + y + gate
__global__ __launch_bounds__(256) void scan_p3(
    const float* __restrict__ u, const float* __restrict__ dt,
    const float* __restrict__ dbc, const float* __restrict__ A_log,
    const float* __restrict__ Dp, const float* __restrict__ Hinit,
    const float* __restrict__ z, float* __restrict__ out)
{
    __shared__ float sdt[TC * 16], su[TC * 16], sB[TC * 16], sC[TC * 16], sY[TC * 16];
    const int tid = threadIdx.x;
    const int n = tid & 15, dl = tid >> 4;
    const int c = blockIdx.x, dg = blockIdx.y;
    const int d = dg * 16 + dl;
    const int t0 = c * TC;
    for (int i = tid; i < TC * 16; i += 256) {
        const int tt = i >> 4, dd = i & 15;
        sdt[i] = dt[(size_t)(t0 + tt) * DINNER + dg * 16 + dd];
        su[i]  = u [(size_t)(t0 + tt) * DINNER + dg * 16 + dd];
        sB[i]  = dbc[(t0 + tt) * DBC_LD + DTRANK + dd];
        sC[i]  = dbc[(t0 + tt) * DBC_LD + DTRANK + DSTATE + dd];
    }
    __syncthreads();
    const float A  = -__expf(A_log[d * DSTATE + n]);
    const float Dv = Dp[d];
    float hs = Hinit[(size_t)c * 32768 + d * DSTATE + n];
    #pragma unroll
    for (int t = 0; t < TC; ++t) {
        const float dtv = sdt[t * 16 + dl];
        const float a = __expf(dtv * A);
        hs = a * hs + (dtv * su[t * 16 + dl]) * sB[t * 16 + n];
        float py = hs * sC[t * 16 + n];
        py += __shfl_xor(py, 1);
        py += __shfl_xor(py, 2);
        py += __shfl_xor(py, 4);
        py += __shfl_xor(py, 8);
        if (n == 0) sY[t * 16 + dl] = py + su[t * 16 + dl] * Dv;
    }
    __syncthreads();
    for (int i = tid; i < TC * 16; i += 256) {
        const int tt = i >> 4, dd = i & 15;
        const float zv = z[(size_t)(t0 + tt) * ISIZE + dg * 16 + dd];
        out[(size_t)(t0 + tt) * DINNER + dg * 16 + dd] = sY[i] * (zv / (1.f + __expf(-zv)));
    }
}

// ---------------------------------------------------------------- x2 = x + rmsnorm(ysum)*mw ; h2 = rmsnorm(x2)*w2
__global__ __launch_bounds__(256) void addnorm2_kernel(
    const float* __restrict__ x0, const float* __restrict__ ys,
    const float* __restrict__ mw, const float* __restrict__ w2,
    float* __restrict__ x2, float* __restrict__ h2)
{
    __shared__ float sred[8];
    const int row = blockIdx.x, t = threadIdx.x;
    float4 yv = ((const float4*)(ys + (size_t)row * DMODEL))[t];
    float ss = yv.x*yv.x + yv.y*yv.y + yv.z*yv.z + yv.w*yv.w;
    #pragma unroll
    for (int m = 1; m < 64; m <<= 1) ss += __shfl_xor(ss, m);
    if ((t & 63) == 0) sred[t >> 6] = ss;
    __syncthreads();
    const float s1 = sred[0] + sred[1] + sred[2] + sred[3];
    const float sc1 = rsqrtf(s1 * (1.f / DMODEL) + 1e-6f);
    float4 xv = ((const float4*)(x0 + (size_t)row * DMODEL))[t];
    float4 mv = ((const float4*)mw)[t];
    float4 o;
    o.x = xv.x + mv.x * yv.x * sc1; o.y = xv.y + mv.y * yv.y * sc1;
    o.z = xv.z + mv.z * yv.z * sc1; o.w = xv.w + mv.w * yv.w * sc1;
    ((float4*)(x2 + (size_t)row * DMODEL))[t] = o;
    float s2 = o.x*o.x + o.y*o.y + o.z*o.z + o.w*o.w;
    #pragma unroll
    for (int m = 1; m < 64; m <<= 1) s2 += __shfl_xor(s2, m);
    if ((t & 63) == 0) sred[4 + (t >> 6)] = s2;
    __syncthreads();
    const float st = sred[4] + sred[5] + sred[6] + sred[7];
    const float sc2 = rsqrtf(st * (1.f / DMODEL) + 1e-6f);
    float4 wv = ((const float4*)w2)[t];
    float4 o2;
    o2.x = wv.x * o.x * sc2; o2.y = wv.y * o.y * sc2;
    o2.z = wv.z * o.z * sc2; o2.w = wv.w * o.w * sc2;
    ((float4*)(h2 + (size_t)row * DMODEL))[t] = o2;
}

// ---------------------------------------------------------------- m = silu(g) * u
__global__ __launch_bounds__(256) void silu_mul_kernel(
    const float* __restrict__ g, const float* __restrict__ u, float* __restrict__ m)
{
    const size_t i = (size_t)blockIdx.x * 256 + threadIdx.x;
    const float gv = g[i], uv = u[i];
    m[i] = gv / (1.f + __expf(-gv)) * uv;
}

// ---------------------------------------------------------------- launch
extern "C" void kernel_launch(void* const* d_in, const int* in_sizes, int n_in,
                              void* d_out, int out_size, void* d_ws, size_t ws_size,
                              hipStream_t stream)
{
    const float* x       = (const float*)d_in[0];
    const float* mask    = (const float*)d_in[1];
    const float* mnorm_w = (const float*)d_in[2];
    const float* ln1_w   = (const float*)d_in[3];
    const float* ln2_w   = (const float*)d_in[4];
    const float* gate_w  = (const float*)d_in[5];
    const float* up_w    = (const float*)d_in[6];
    const float* down_w  = (const float*)d_in[7];
    const float* in_w[2]    = {(const float*)d_in[8],  (const float*)d_in[17]};
    const float* conv_w[2]  = {(const float*)d_in[9],  (const float*)d_in[18]};
    const float* conv_b[2]  = {(const float*)d_in[10], (const float*)d_in[19]};
    const float* xproj_w[2] = {(const float*)d_in[11], (const float*)d_in[20]};
    const float* dt_w[2]    = {(const float*)d_in[12], (const float*)d_in[21]};
    const float* dt_b[2]    = {(const float*)d_in[13], (const float*)d_in[22]};
    const float* A_log[2]   = {(const float*)d_in[14], (const float*)d_in[23]};
    const float* Dp[2]      = {(const float*)d_in[15], (const float*)d_in[24]};
    const float* out_w[2]   = {(const float*)d_in[16], (const float*)d_in[25]};

    float* ws = (float*)d_ws;
    const size_t S1 = (size_t)L_SEQ * DMODEL;       // 2M floats
    float* h     = ws;                // L x 1024
    float* hrev  = ws + S1;           // L x 1024
    float* ysum  = ws + 2 * S1;       // L x 1024
    float* x2    = ws + 3 * S1;       // L x 1024 (Hinit during scans)
    float* bufA  = ws + 4 * S1;       // L x 4096 : xz / mlp-gate (xi half hosts P/S during scans)
    float* xc    = ws + 8 * S1;       // L x 2048
    float* dtb   = ws + 10 * S1;      // L x 2048
    float* ygate = ws + 12 * S1;      // L x 2048
    float* dbc   = ws + 14 * S1;      // L x 96
    float* ubuf  = ws + 8 * S1;       // MLP up   (reuses xc+dtb)
    float* mbuf  = ws + 12 * S1;      // MLP mid  (reuses ygate+dbc)

    float* Pb    = bufA;                        // rows 0..1023 of xi half
    float* Sb    = bufA + (size_t)1024 * 4096;  // rows 1024..2047 of xi half
    float* Hinit = x2;

    rmsnorm_mask_kernel<<<L_SEQ, 256, 0, stream>>>(x, ln1_w, mask, h, hrev);

    for (int dir = 0; dir < 2; ++dir) {
        const float* hd = dir ? hrev : h;
        // xz = h @ in_w^T            (2048 x 4096, K=1024)
        gemm_nt<0, false><<<dim3(32, 64), 256, 0, stream>>>(
            hd, in_w[dir], bufA, nullptr, 2048, 4096, 1024, 1024, 1024, 4096);
        // xc = silu(causal_conv(xi))
        conv_silu_kernel<<<(L_SEQ * DINNER) / 256, 256, 0, stream>>>(
            bufA, conv_w[dir], conv_b[dir], xc);
        // dbc = xc @ xproj^T         (2048 x 96, K=2048)
        gemm_nt<0, false><<<dim3(32, 2), 256, 0, stream>>>(
            xc, xproj_w[dir], dbc, nullptr, 2048, 96, 2048, 2048, 2048, 96);
        // dt = softplus(dt_raw @ dt_w^T + dt_b)   (2048 x 2048, K=64)
        gemm_nt<1, false><<<dim3(32, 32), 256, 0, stream>>>(
            dbc, dt_w[dir], dtb, dt_b[dir], 2048, 2048, 64, 96, 64, 2048);
        // chunk-parallel selective scan + Dp skip + silu(z) gating
        scan_p1<<<dim3(NC, DINNER / 16), 256, 0, stream>>>(
            xc, dtb, dbc, A_log[dir], Pb, Sb);
        scan_mid<<<(DINNER * DSTATE) / 256, 256, 0, stream>>>(Pb, Sb, Hinit);
        scan_p3<<<dim3(NC, DINNER / 16), 256, 0, stream>>>(
            xc, dtb, dbc, A_log[dir], Dp[dir], Hinit, bufA + DINNER, ygate);
        // out-proj (fwd: store; bwd: accumulate with row flip)
        if (dir == 0)
            gemm_nt<0, false><<<dim3(32, 16), 256, 0, stream>>>(
                ygate, out_w[0], ysum, nullptr, 2048, 1024, 2048, 2048, 2048, 1024);
        else
            gemm_nt<2, true><<<dim3(32, 16), 256, 0, stream>>>(
                ygate, out_w[1], ysum, nullptr, 2048, 1024, 2048, 2048, 2048, 1024);
    }

    // x2 = x + rmsnorm(ysum)*mnorm_w ; h2 = rmsnorm(x2)*ln2_w  (h2 stored in h)
    addnorm2_kernel<<<L_SEQ, 256, 0, stream>>>(x, ysum, mnorm_w, ln2_w, x2, h);

    // MLP
    gemm_nt<0, false><<<dim3(32, 64), 256, 0, stream>>>(
        h, gate_w, bufA, nullptr, 2048, 4096, 1024, 1024, 1024, 4096);
    gemm_nt<0, false><<<dim3(32, 64), 256, 0, stream>>>(
        h, up_w, ubuf, nullptr, 2048, 4096, 1024, 1024, 1024, 4096);
    silu_mul_kernel<<<(L_SEQ * ISIZE) / 256, 256, 0, stream>>>(bufA, ubuf, mbuf);
    gemm_nt<3, false><<<dim3(32, 16), 256, 0, stream>>>(
        mbuf, down_w, (float*)d_out, x2, 2048, 1024, 4096, 4096, 4096, 1024);
}

// Round 3
// 690.926 us; speedup vs baseline: 5.6666x; 1.1850x over previous
//
#include <hip/hip_runtime.h>

#define L_SEQ 2048
#define DMODEL 1024
#define DINNER 2048
#define DSTATE 16
#define DTRANK 64
#define DBC_LD 96
#define ISIZE 4096
#define NC 64   // scan chunks
#define TC 32   // timesteps per chunk

typedef __bf16 bf16x8 __attribute__((ext_vector_type(8)));
typedef __bf16 bf16x4 __attribute__((ext_vector_type(4)));
typedef float f32x4 __attribute__((ext_vector_type(4)));

__device__ __forceinline__ void gload_lds16(const void* g, void* l) {
    __builtin_amdgcn_global_load_lds(
        (const __attribute__((address_space(1))) void*)g,
        (__attribute__((address_space(3))) void*)l, 16, 0, 0);
}

// ---------------------------------------------------------------- bf16 GEMM NT (m97 structure)
// C[r][c] = sum_k A[r][k] * W[c][k]; A: MxK bf16 (lda), W: NxK bf16 (ldb), C f32 (ldc)
// 128x128 tile, 4 waves (2x2), BK=64, global_load_lds + XOR-swizzled LDS.
// EPI: 0=store, 1=softplus(acc+aux[c]), 2=C[M-1-r]+=acc, 3=C=aux[r*ldc+c]+acc,
//      4=store f32 + bf16 dup of cols<DTRANK into Cb[r*DTRANK+c]
template<int EPI>
__global__ __launch_bounds__(256) void gemm16(
    const __bf16* __restrict__ A, const __bf16* __restrict__ W,
    float* __restrict__ C, const float* __restrict__ aux,
    __bf16* __restrict__ Cb,
    int M, int N, int K, int lda, int ldb, int ldc)
{
    __shared__ __bf16 lsA[128 * 64];
    __shared__ __bf16 lsB[128 * 64];
    const int tid  = threadIdx.x;
    const int lane = tid & 63;
    const int wave = tid >> 6;
    const int wr = wave >> 1, wc = wave & 1;          // 2x2 wave grid, 64x64 each
    const int m0 = blockIdx.x * 128, n0 = blockIdx.y * 128;

    // staging: slot s = wave*256 + i*64 + lane; row = s>>3, q = s&7 (16B quad)
    const int q  = lane & 7;
    const int rb = wave * 32 + (lane >> 3);           // + i*8

    f32x4 acc[4][4] = {};

    for (int k0 = 0; k0 < K; k0 += 64) {
        #pragma unroll
        for (int i = 0; i < 4; ++i) {
            const int row = rb + i * 8;
            const int sk  = (q * 8) ^ ((row & 7) << 3);   // pre-swizzled source (elems)
            gload_lds16(A + (size_t)(m0 + row) * lda + k0 + sk,
                        &lsA[(wave * 4 + i) * 512]);
            int rw = n0 + row; rw = rw < N ? rw : N - 1;  // clamp for N<128 tiles
            gload_lds16(W + (size_t)rw * ldb + k0 + sk,
                        &lsB[(wave * 4 + i) * 512]);
        }
        __syncthreads();   // drains vmcnt -> LDS ready
        #pragma unroll
        for (int kk = 0; kk < 2; ++kk) {
            bf16x8 af[4], bf[4];
            #pragma unroll
            for (int m = 0; m < 4; ++m) {
                const int row = wr * 64 + m * 16 + (lane & 15);
                const int kb  = (kk * 32 + (lane >> 4) * 8) ^ ((row & 7) << 3);
                af[m] = *(const bf16x8*)&lsA[row * 64 + kb];
            }
            #pragma unroll
            for (int n = 0; n < 4; ++n) {
                const int row = wc * 64 + n * 16 + (lane & 15);
                const int kb  = (kk * 32 + (lane >> 4) * 8) ^ ((row & 7) << 3);
                bf[n] = *(const bf16x8*)&lsB[row * 64 + kb];
            }
            #pragma unroll
            for (int m = 0; m < 4; ++m)
            #pragma unroll
            for (int n = 0; n < 4; ++n)
                acc[m][n] = __builtin_amdgcn_mfma_f32_16x16x32_bf16(af[m], bf[n], acc[m][n], 0, 0, 0);
        }
        __syncthreads();   // protect LDS before next-stage overwrite
    }

    const int cr = (lane >> 4) * 4, cc = lane & 15;
    #pragma unroll
    for (int mi = 0; mi < 4; ++mi)
    #pragma unroll
    for (int ni = 0; ni < 4; ++ni) {
        const int c = n0 + wc * 64 + ni * 16 + cc;
        if (c >= N) continue;
        #pragma unroll
        for (int g = 0; g < 4; ++g) {
            const int r = m0 + wr * 64 + mi * 16 + cr + g;
            float v = acc[mi][ni][g];
            if (EPI == 0) {
                C[(size_t)r * ldc + c] = v;
            } else if (EPI == 1) {
                float xv = v + aux[c];
                C[(size_t)r * ldc + c] = (xv > 20.f) ? xv : log1pf(__expf(xv));
            } else if (EPI == 2) {
                C[(size_t)(M - 1 - r) * ldc + c] += v;
            } else if (EPI == 3) {
                C[(size_t)r * ldc + c] = aux[(size_t)r * ldc + c] + v;
            } else {
                C[(size_t)r * ldc + c] = v;
                if (c < DTRANK) Cb[(size_t)r * DTRANK + c] = (__bf16)v;
            }
        }
    }
}

// ---------------------------------------------------------------- batched f32 -> bf16 weight convert
#define NJOBS 11
struct CvtJobs {
    const float* src[NJOBS];
    __bf16* dst[NJOBS];
    int cum[NJOBS + 1];   // prefix sums, units of 8 elems
};
__global__ __launch_bounds__(256) void cvt_multi(CvtJobs j, int total8) {
    const int g = blockIdx.x * 256 + threadIdx.x;
    if (g >= total8) return;
    for (int i = 0; i < NJOBS; ++i) {
        if (g < j.cum[i + 1]) {
            const int off = (g - j.cum[i]) * 8;
            const float4 a = *(const float4*)(j.src[i] + off);
            const float4 b = *(const float4*)(j.src[i] + off + 4);
            bf16x8 o;
            o[0]=(__bf16)a.x; o[1]=(__bf16)a.y; o[2]=(__bf16)a.z; o[3]=(__bf16)a.w;
            o[4]=(__bf16)b.x; o[5]=(__bf16)b.y; o[6]=(__bf16)b.z; o[7]=(__bf16)b.w;
            *(bf16x8*)(j.dst[i] + off) = o;
            return;
        }
    }
}

// ---------------------------------------------------------------- rmsnorm1 (+mask) -> bf16 h + flipped bf16 h
__global__ __launch_bounds__(256) void rmsnorm_mask_kernel(
    const float* __restrict__ x, const float* __restrict__ w, const float* __restrict__ mask,
    __bf16* __restrict__ h16, __bf16* __restrict__ hrev16)
{
    __shared__ float sred[4];
    const int row = blockIdx.x, t = threadIdx.x;
    float4 v = ((const float4*)(x + (size_t)row * DMODEL))[t];
    float ss = v.x*v.x + v.y*v.y + v.z*v.z + v.w*v.w;
    #pragma unroll
    for (int m = 1; m < 64; m <<= 1) ss += __shfl_xor(ss, m);
    if ((t & 63) == 0) sred[t >> 6] = ss;
    __syncthreads();
    ss = sred[0] + sred[1] + sred[2] + sred[3];
    const float scale = rsqrtf(ss * (1.f / DMODEL) + 1e-6f) * mask[row];
    float4 wv = ((const float4*)w)[t];
    bf16x4 o;
    o[0] = (__bf16)(v.x * wv.x * scale); o[1] = (__bf16)(v.y * wv.y * scale);
    o[2] = (__bf16)(v.z * wv.z * scale); o[3] = (__bf16)(v.w * wv.w * scale);
    *(bf16x4*)&h16[(size_t)row * DMODEL + t * 4] = o;
    *(bf16x4*)&hrev16[(size_t)(L_SEQ - 1 - row) * DMODEL + t * 4] = o;
}

// ---------------------------------------------------------------- causal depthwise conv (k=4) + silu
__global__ __launch_bounds__(256) void conv_silu_kernel(
    const float* __restrict__ xz, const float* __restrict__ w,
    const float* __restrict__ b, float* __restrict__ xc, __bf16* __restrict__ xc16)
{
    const int idx = blockIdx.x * 256 + threadIdx.x;   // over L*DINNER
    const int d = idx & (DINNER - 1);
    const int t = idx >> 11;
    float acc = b[d];
    const float4 wv = *(const float4*)(w + d * 4);
    const float wj[4] = {wv.x, wv.y, wv.z, wv.w};
    #pragma unroll
    for (int j = 0; j < 4; ++j) {
        const int tt = t - 3 + j;
        if (tt >= 0) acc += wj[j] * xz[(size_t)tt * ISIZE + d];
    }
    const float val = acc / (1.f + __expf(-acc));
    xc[(size_t)idx] = val;
    xc16[(size_t)idx] = (__bf16)val;
}

// ---------------------------------------------------------------- scan phase 1: per-chunk summaries
__global__ __launch_bounds__(256) void scan_p1(
    const float* __restrict__ u, const float* __restrict__ dt,
    const float* __restrict__ dbc, const float* __restrict__ A_log,
    float* __restrict__ Pb, float* __restrict__ Sb)
{
    __shared__ float sdt[TC * 16], su[TC * 16], sB[TC * 16];
    const int tid = threadIdx.x;
    const int n = tid & 15, dl = tid >> 4;
    const int c = blockIdx.x, dg = blockIdx.y;
    const int d = dg * 16 + dl;
    const int t0 = c * TC;
    for (int i = tid; i < TC * 16; i += 256) {
        const int tt = i >> 4, dd = i & 15;
        sdt[i] = dt[(size_t)(t0 + tt) * DINNER + dg * 16 + dd];
        su[i]  = u [(size_t)(t0 + tt) * DINNER + dg * 16 + dd];
        sB[i]  = dbc[(t0 + tt) * DBC_LD + DTRANK + dd];
    }
    __syncthreads();
    const float A = -__expf(A_log[d * DSTATE + n]);
    float hs = 0.f, Pa = 1.f;
    #pragma unroll
    for (int t = 0; t < TC; ++t) {
        const float dtv = sdt[t * 16 + dl];
        const float a = __expf(dtv * A);
        hs = a * hs + (dtv * su[t * 16 + dl]) * sB[t * 16 + n];
        Pa *= a;
    }
    const int idn = d * DSTATE + n;
    Pb[(size_t)c * 32768 + idn] = Pa;
    Sb[(size_t)c * 32768 + idn] = hs;
}

// ---------------------------------------------------------------- scan phase 2: combine chunk states
__global__ __launch_bounds__(256) void scan_mid(
    const float* __restrict__ Pb, const float* __restrict__ Sb, float* __restrict__ Hinit)
{
    const int i = blockIdx.x * 256 + threadIdx.x;   // (d,n) index
    float H = 0.f;
    for (int c = 0; c < NC; ++c) {
        Hinit[(size_t)c * 32768 + i] = H;
        H = Pb[(size_t)c * 32768 + i] * H + Sb[(size_t)c * 32768 + i];
    }
}

// ---------------------------------------------------------------- scan phase 3: recompute + y + gate -> bf16
__global__ __launch_bounds__(256) void scan_p3(
    const float* __restrict__ u, const float* __restrict__ dt,
    const float* __restrict__ dbc, const float* __restrict__ A_log,
    const float* __restrict__ Dp, const float* __restrict__ Hinit,
    const float* __restrict__ z, __bf16* __restrict__ out16)
{
    __shared__ float sdt[TC * 16], su[TC * 16], sB[TC * 16], sC[TC * 16], sY[TC * 16];
    const int tid = threadIdx.x;
    const int n = tid & 15, dl = tid >> 4;
    const int c = blockIdx.x, dg = blockIdx.y;
    const int d = dg * 16 + dl;
    const int t0 = c * TC;
    for (int i = tid; i < TC * 16; i += 256) {
        const int tt = i >> 4, dd = i & 15;
        sdt[i] = dt[(size_t)(t0 + tt) * DINNER + dg * 16 + dd];
        su[i]  = u [(size_t)(t0 + tt) * DINNER + dg * 16 + dd];
        sB[i]  = dbc[(t0 + tt) * DBC_LD + DTRANK + dd];
        sC[i]  = dbc[(t0 + tt) * DBC_LD + DTRANK + DSTATE + dd];
    }
    __syncthreads();
    const float A  = -__expf(A_log[d * DSTATE + n]);
    const float Dv = Dp[d];
    float hs = Hinit[(size_t)c * 32768 + d * DSTATE + n];
    #pragma unroll
    for (int t = 0; t < TC; ++t) {
        const float dtv = sdt[t * 16 + dl];
        const float a = __expf(dtv * A);
        hs = a * hs + (dtv * su[t * 16 + dl]) * sB[t * 16 + n];
        float py = hs * sC[t * 16 + n];
        py += __shfl_xor(py, 1);
        py += __shfl_xor(py, 2);
        py += __shfl_xor(py, 4);
        py += __shfl_xor(py, 8);
        if (n == 0) sY[t * 16 + dl] = py + su[t * 16 + dl] * Dv;
    }
    __syncthreads();
    for (int i = tid; i < TC * 16; i += 256) {
        const int tt = i >> 4, dd = i & 15;
        const float zv = z[(size_t)(t0 + tt) * ISIZE + dg * 16 + dd];
        out16[(size_t)(t0 + tt) * DINNER + dg * 16 + dd] =
            (__bf16)(sY[i] * (zv / (1.f + __expf(-zv))));
    }
}

// ---------------------------------------------------------------- x2 = x + rmsnorm(ysum)*mw ; h2_16 = bf16(rmsnorm(x2)*w2)
__global__ __launch_bounds__(256) void addnorm2_kernel(
    const float* __restrict__ x0, const float* __restrict__ ys,
    const float* __restrict__ mw, const float* __restrict__ w2,
    float* __restrict__ x2, __bf16* __restrict__ h2_16)
{
    __shared__ float sred[8];
    const int row = blockIdx.x, t = threadIdx.x;
    float4 yv = ((const float4*)(ys + (size_t)row * DMODEL))[t];
    float ss = yv.x*yv.x + yv.y*yv.y + yv.z*yv.z + yv.w*yv.w;
    #pragma unroll
    for (int m = 1; m < 64; m <<= 1) ss += __shfl_xor(ss, m);
    if ((t & 63) == 0) sred[t >> 6] = ss;
    __syncthreads();
    const float s1 = sred[0] + sred[1] + sred[2] + sred[3];
    const float sc1 = rsqrtf(s1 * (1.f / DMODEL) + 1e-6f);
    float4 xv = ((const float4*)(x0 + (size_t)row * DMODEL))[t];
    float4 mv = ((const float4*)mw)[t];
    float4 o;
    o.x = xv.x + mv.x * yv.x * sc1; o.y = xv.y + mv.y * yv.y * sc1;
    o.z = xv.z + mv.z * yv.z * sc1; o.w = xv.w + mv.w * yv.w * sc1;
    ((float4*)(x2 + (size_t)row * DMODEL))[t] = o;
    float s2 = o.x*o.x + o.y*o.y + o.z*o.z + o.w*o.w;
    #pragma unroll
    for (int m = 1; m < 64; m <<= 1) s2 += __shfl_xor(s2, m);
    if ((t & 63) == 0) sred[4 + (t >> 6)] = s2;
    __syncthreads();
    const float st = sred[4] + sred[5] + sred[6] + sred[7];
    const float sc2 = rsqrtf(st * (1.f / DMODEL) + 1e-6f);
    float4 wv = ((const float4*)w2)[t];
    bf16x4 o2;
    o2[0] = (__bf16)(wv.x * o.x * sc2); o2[1] = (__bf16)(wv.y * o.y * sc2);
    o2[2] = (__bf16)(wv.z * o.z * sc2); o2[3] = (__bf16)(wv.w * o.w * sc2);
    *(bf16x4*)&h2_16[(size_t)row * DMODEL + t * 4] = o2;
}

// ---------------------------------------------------------------- m16 = bf16(silu(g) * u)
__global__ __launch_bounds__(256) void silu_mul_kernel(
    const float* __restrict__ g, const float* __restrict__ u, __bf16* __restrict__ m16)
{
    const size_t i8 = ((size_t)blockIdx.x * 256 + threadIdx.x) * 8;
    const float4 g0 = *(const float4*)(g + i8), g1 = *(const float4*)(g + i8 + 4);
    const float4 u0 = *(const float4*)(u + i8), u1 = *(const float4*)(u + i8 + 4);
    bf16x8 o;
    o[0] = (__bf16)(g0.x / (1.f + __expf(-g0.x)) * u0.x);
    o[1] = (__bf16)(g0.y / (1.f + __expf(-g0.y)) * u0.y);
    o[2] = (__bf16)(g0.z / (1.f + __expf(-g0.z)) * u0.z);
    o[3] = (__bf16)(g0.w / (1.f + __expf(-g0.w)) * u0.w);
    o[4] = (__bf16)(g1.x / (1.f + __expf(-g1.x)) * u1.x);
    o[5] = (__bf16)(g1.y / (1.f + __expf(-g1.y)) * u1.y);
    o[6] = (__bf16)(g1.z / (1.f + __expf(-g1.z)) * u1.z);
    o[7] = (__bf16)(g1.w / (1.f + __expf(-g1.w)) * u1.w);
    *(bf16x8*)(m16 + i8) = o;
}

// ---------------------------------------------------------------- launch
extern "C" void kernel_launch(void* const* d_in, const int* in_sizes, int n_in,
                              void* d_out, int out_size, void* d_ws, size_t ws_size,
                              hipStream_t stream)
{
    const float* x       = (const float*)d_in[0];
    const float* mask    = (const float*)d_in[1];
    const float* mnorm_w = (const float*)d_in[2];
    const float* ln1_w   = (const float*)d_in[3];
    const float* ln2_w   = (const float*)d_in[4];
    const float* gate_w  = (const float*)d_in[5];
    const float* up_w    = (const float*)d_in[6];
    const float* down_w  = (const float*)d_in[7];
    const float* in_w[2]    = {(const float*)d_in[8],  (const float*)d_in[17]};
    const float* conv_w[2]  = {(const float*)d_in[9],  (const float*)d_in[18]};
    const float* conv_b[2]  = {(const float*)d_in[10], (const float*)d_in[19]};
    const float* xproj_w[2] = {(const float*)d_in[11], (const float*)d_in[20]};
    const float* dt_w[2]    = {(const float*)d_in[12], (const float*)d_in[21]};
    const float* dt_b[2]    = {(const float*)d_in[13], (const float*)d_in[22]};
    const float* A_log[2]   = {(const float*)d_in[14], (const float*)d_in[23]};
    const float* Dp[2]      = {(const float*)d_in[15], (const float*)d_in[24]};
    const float* out_w[2]   = {(const float*)d_in[16], (const float*)d_in[25]};

    float* ws = (float*)d_ws;
    const size_t MF = 1u << 20;                    // 1M floats
    __bf16* h16     = (__bf16*)(ws + 0 * MF);      // 2M bf16
    __bf16* hrev16  = (__bf16*)(ws + 1 * MF);      // 2M bf16
    float*  ysum    = ws + 2 * MF;                 // 2M f32
    float*  x2      = ws + 4 * MF;                 // 2M f32
    float*  xz      = ws + 6 * MF;                 // 8M f32 (also MLP gate out)
    float*  xc      = ws + 14 * MF;                // 4M f32 (with dtb: MLP up out)
    float*  dtb     = ws + 18 * MF;                // 4M f32
    __bf16* xc16    = (__bf16*)(ws + 22 * MF);     // 4M bf16
    __bf16* ygate16 = (__bf16*)(ws + 24 * MF);     // 4M bf16
    float*  dbc     = ws + 26 * MF;                // L*96 f32
    __bf16* dbc16   = (__bf16*)(ws + 26 * MF + 262144);  // L*64 bf16
    float*  Pb      = ws + 26 * MF + 524288;       // 2M f32   (scan phase only)
    float*  Sb      = ws + 28 * MF + 524288;       // 2M f32
    float*  Hinit   = ws + 30 * MF + 524288;       // 2M f32
    __bf16* h2_16   = (__bf16*)(ws + 26 * MF + 524288);  // reuse Pb post-scan, 2M bf16
    __bf16* mbuf16  = (__bf16*)(ws + 27 * MF + 524288);  // reuse, 8M bf16
    __bf16* wbase   = (__bf16*)(ws + 33 * MF);     // bf16 weights
    const size_t M4 = 4u << 20, M2 = 2u << 20;
    __bf16* wIN[2]  = {wbase,             wbase + M4};
    __bf16* wOUT[2] = {wbase + 2 * M4,    wbase + 2 * M4 + M2};
    __bf16* wG      = wbase + 3 * M4;
    __bf16* wU      = wbase + 4 * M4;
    __bf16* wDN     = wbase + 5 * M4;
    __bf16* wXP[2]  = {wbase + 6 * M4,            wbase + 6 * M4 + 196608};
    __bf16* wDT[2]  = {wbase + 6 * M4 + 393216,   wbase + 6 * M4 + 524288};

    // ---- weight conversion (single batched kernel)
    CvtJobs j;
    const float* srcs[NJOBS] = {in_w[0], in_w[1], out_w[0], out_w[1], gate_w, up_w, down_w,
                                xproj_w[0], xproj_w[1], dt_w[0], dt_w[1]};
    __bf16* dsts[NJOBS] = {wIN[0], wIN[1], wOUT[0], wOUT[1], wG, wU, wDN,
                           wXP[0], wXP[1], wDT[0], wDT[1]};
    const int szs[NJOBS] = {4194304, 4194304, 2097152, 2097152, 4194304, 4194304, 4194304,
                            196608, 196608, 131072, 131072};
    int cum = 0;
    for (int i = 0; i < NJOBS; ++i) {
        j.src[i] = srcs[i]; j.dst[i] = dsts[i]; j.cum[i] = cum; cum += szs[i] / 8;
    }
    j.cum[NJOBS] = cum;
    cvt_multi<<<(cum + 255) / 256, 256, 0, stream>>>(j, cum);

    rmsnorm_mask_kernel<<<L_SEQ, 256, 0, stream>>>(x, ln1_w, mask, h16, hrev16);

    for (int dir = 0; dir < 2; ++dir) {
        const __bf16* hd = dir ? hrev16 : h16;
        // xz = h @ in_w^T            (2048 x 4096, K=1024)
        gemm16<0><<<dim3(16, 32), 256, 0, stream>>>(
            hd, wIN[dir], xz, nullptr, nullptr, 2048, 4096, 1024, 1024, 1024, 4096);
        // xc = silu(causal_conv(xi)), dual f32+bf16
        conv_silu_kernel<<<(L_SEQ * DINNER) / 256, 256, 0, stream>>>(
            xz, conv_w[dir], conv_b[dir], xc, xc16);
        // dbc = xc @ xproj^T         (2048 x 96, K=2048), + bf16 dup of dt_raw cols
        gemm16<4><<<dim3(16, 1), 256, 0, stream>>>(
            xc16, wXP[dir], dbc, nullptr, dbc16, 2048, 96, 2048, 2048, 2048, 96);
        // dt = softplus(dt_raw @ dt_w^T + dt_b)   (2048 x 2048, K=64)
        gemm16<1><<<dim3(16, 16), 256, 0, stream>>>(
            dbc16, wDT[dir], dtb, dt_b[dir], nullptr, 2048, 2048, 64, 64, 64, 2048);
        // chunk-parallel selective scan + Dp skip + silu(z) gating -> bf16
        scan_p1<<<dim3(NC, DINNER / 16), 256, 0, stream>>>(
            xc, dtb, dbc, A_log[dir], Pb, Sb);
        scan_mid<<<(DINNER * DSTATE) / 256, 256, 0, stream>>>(Pb, Sb, Hinit);
        scan_p3<<<dim3(NC, DINNER / 16), 256, 0, stream>>>(
            xc, dtb, dbc, A_log[dir], Dp[dir], Hinit, xz + DINNER, ygate16);
        // out-proj (fwd: store; bwd: accumulate with row flip)
        if (dir == 0)
            gemm16<0><<<dim3(16, 8), 256, 0, stream>>>(
                ygate16, wOUT[0], ysum, nullptr, nullptr, 2048, 1024, 2048, 2048, 2048, 1024);
        else
            gemm16<2><<<dim3(16, 8), 256, 0, stream>>>(
                ygate16, wOUT[1], ysum, nullptr, nullptr, 2048, 1024, 2048, 2048, 2048, 1024);
    }

    // x2 = x + rmsnorm(ysum)*mnorm_w ; h2_16 = bf16(rmsnorm(x2)*ln2_w)
    addnorm2_kernel<<<L_SEQ, 256, 0, stream>>>(x, ysum, mnorm_w, ln2_w, x2, h2_16);

    // MLP
    gemm16<0><<<dim3(16, 32), 256, 0, stream>>>(
        h2_16, wG, xz, nullptr, nullptr, 2048, 4096, 1024, 1024, 1024, 4096);
    gemm16<0><<<dim3(16, 32), 256, 0, stream>>>(
        h2_16, wU, xc, nullptr, nullptr, 2048, 4096, 1024, 1024, 1024, 4096);
    silu_mul_kernel<<<(L_SEQ * ISIZE) / (256 * 8), 256, 0, stream>>>(xz, xc, mbuf16);
    gemm16<3><<<dim3(16, 8), 256, 0, stream>>>(
        mbuf16, wDN, (float*)d_out, x2, nullptr, 2048, 1024, 4096, 4096, 4096, 1024);
}

// Round 4
// 615.249 us; speedup vs baseline: 6.3636x; 1.1230x over previous
//
#include <hip/hip_runtime.h>

#define L_SEQ 2048
#define DMODEL 1024
#define DINNER 2048
#define DSTATE 16
#define DTRANK 64
#define DBC_LD 96
#define ISIZE 4096
#define NC 64   // scan chunks
#define TC 32   // timesteps per chunk

typedef __bf16 bf16x8 __attribute__((ext_vector_type(8)));
typedef __bf16 bf16x4 __attribute__((ext_vector_type(4)));
typedef float f32x4 __attribute__((ext_vector_type(4)));

__device__ __forceinline__ void gload_lds16(const void* g, void* l) {
    __builtin_amdgcn_global_load_lds(
        (const __attribute__((address_space(1))) void*)g,
        (__attribute__((address_space(3))) void*)l, 16, 0, 0);
}

// ---------------------------------------------------------------- bf16 GEMM NT (m97 structure)
// C[r][c] = sum_k A[r][k] * W[c][k]; A: MxK bf16 (lda), W: NxK bf16 (ldb), C f32 (ldc)
// 128x128 tile, 4 waves (2x2), BK=64, global_load_lds + XOR-swizzled LDS.
// EPI: 0=store, 1=softplus(acc+aux[c]), 2=C[M-1-r]+=acc, 3=C=aux[r*ldc+c]+acc,
//      4=store f32 + bf16 dup of cols<DTRANK into Cb[r*DTRANK+c]
template<int EPI>
__global__ __launch_bounds__(256) void gemm16(
    const __bf16* __restrict__ A, const __bf16* __restrict__ W,
    float* __restrict__ C, const float* __restrict__ aux,
    __bf16* __restrict__ Cb,
    int M, int N, int K, int lda, int ldb, int ldc)
{
    __shared__ __bf16 lsA[128 * 64];
    __shared__ __bf16 lsB[128 * 64];
    const int tid  = threadIdx.x;
    const int lane = tid & 63;
    const int wave = tid >> 6;
    const int wr = wave >> 1, wc = wave & 1;          // 2x2 wave grid, 64x64 each
    const int m0 = blockIdx.x * 128, n0 = blockIdx.y * 128;

    // staging: slot s = wave*256 + i*64 + lane; row = s>>3, q = s&7 (16B quad)
    const int q  = lane & 7;
    const int rb = wave * 32 + (lane >> 3);           // + i*8

    f32x4 acc[4][4] = {};

    for (int k0 = 0; k0 < K; k0 += 64) {
        #pragma unroll
        for (int i = 0; i < 4; ++i) {
            const int row = rb + i * 8;
            const int sk  = (q * 8) ^ ((row & 7) << 3);   // pre-swizzled source (elems)
            gload_lds16(A + (size_t)(m0 + row) * lda + k0 + sk,
                        &lsA[(wave * 4 + i) * 512]);
            int rw = n0 + row; rw = rw < N ? rw : N - 1;  // clamp for N<128 tiles
            gload_lds16(W + (size_t)rw * ldb + k0 + sk,
                        &lsB[(wave * 4 + i) * 512]);
        }
        __syncthreads();   // drains vmcnt -> LDS ready
        #pragma unroll
        for (int kk = 0; kk < 2; ++kk) {
            bf16x8 af[4], bf[4];
            #pragma unroll
            for (int m = 0; m < 4; ++m) {
                const int row = wr * 64 + m * 16 + (lane & 15);
                const int kb  = (kk * 32 + (lane >> 4) * 8) ^ ((row & 7) << 3);
                af[m] = *(const bf16x8*)&lsA[row * 64 + kb];
            }
            #pragma unroll
            for (int n = 0; n < 4; ++n) {
                const int row = wc * 64 + n * 16 + (lane & 15);
                const int kb  = (kk * 32 + (lane >> 4) * 8) ^ ((row & 7) << 3);
                bf[n] = *(const bf16x8*)&lsB[row * 64 + kb];
            }
            #pragma unroll
            for (int m = 0; m < 4; ++m)
            #pragma unroll
            for (int n = 0; n < 4; ++n)
                acc[m][n] = __builtin_amdgcn_mfma_f32_16x16x32_bf16(af[m], bf[n], acc[m][n], 0, 0, 0);
        }
        __syncthreads();   // protect LDS before next-stage overwrite
    }

    const int cr = (lane >> 4) * 4, cc = lane & 15;
    #pragma unroll
    for (int mi = 0; mi < 4; ++mi)
    #pragma unroll
    for (int ni = 0; ni < 4; ++ni) {
        const int c = n0 + wc * 64 + ni * 16 + cc;
        if (c >= N) continue;
        #pragma unroll
        for (int g = 0; g < 4; ++g) {
            const int r = m0 + wr * 64 + mi * 16 + cr + g;
            float v = acc[mi][ni][g];
            if (EPI == 0) {
                C[(size_t)r * ldc + c] = v;
            } else if (EPI == 1) {
                float xv = v + aux[c];
                C[(size_t)r * ldc + c] = (xv > 20.f) ? xv : log1pf(__expf(xv));
            } else if (EPI == 2) {
                C[(size_t)(M - 1 - r) * ldc + c] += v;
            } else if (EPI == 3) {
                C[(size_t)r * ldc + c] = aux[(size_t)r * ldc + c] + v;
            } else {
                C[(size_t)r * ldc + c] = v;
                if (c < DTRANK) Cb[(size_t)r * DTRANK + c] = (__bf16)v;
            }
        }
    }
}

// ---------------------------------------------------------------- batched f32 -> bf16 weight convert
#define NJOBS 11
struct CvtJobs {
    const float* src[NJOBS];
    __bf16* dst[NJOBS];
    int cum[NJOBS + 1];   // prefix sums, units of 8 elems
};
__global__ __launch_bounds__(256) void cvt_multi(CvtJobs j, int total8) {
    const int g = blockIdx.x * 256 + threadIdx.x;
    if (g >= total8) return;
    for (int i = 0; i < NJOBS; ++i) {
        if (g < j.cum[i + 1]) {
            const int off = (g - j.cum[i]) * 8;
            const float4 a = *(const float4*)(j.src[i] + off);
            const float4 b = *(const float4*)(j.src[i] + off + 4);
            bf16x8 o;
            o[0]=(__bf16)a.x; o[1]=(__bf16)a.y; o[2]=(__bf16)a.z; o[3]=(__bf16)a.w;
            o[4]=(__bf16)b.x; o[5]=(__bf16)b.y; o[6]=(__bf16)b.z; o[7]=(__bf16)b.w;
            *(bf16x8*)(j.dst[i] + off) = o;
            return;
        }
    }
}

// ---------------------------------------------------------------- rmsnorm1 (+mask) -> bf16 h + flipped bf16 h
__global__ __launch_bounds__(256) void rmsnorm_mask_kernel(
    const float* __restrict__ x, const float* __restrict__ w, const float* __restrict__ mask,
    __bf16* __restrict__ h16, __bf16* __restrict__ hrev16)
{
    __shared__ float sred[4];
    const int row = blockIdx.x, t = threadIdx.x;
    float4 v = ((const float4*)(x + (size_t)row * DMODEL))[t];
    float ss = v.x*v.x + v.y*v.y + v.z*v.z + v.w*v.w;
    #pragma unroll
    for (int m = 1; m < 64; m <<= 1) ss += __shfl_xor(ss, m);
    if ((t & 63) == 0) sred[t >> 6] = ss;
    __syncthreads();
    ss = sred[0] + sred[1] + sred[2] + sred[3];
    const float scale = rsqrtf(ss * (1.f / DMODEL) + 1e-6f) * mask[row];
    float4 wv = ((const float4*)w)[t];
    bf16x4 o;
    o[0] = (__bf16)(v.x * wv.x * scale); o[1] = (__bf16)(v.y * wv.y * scale);
    o[2] = (__bf16)(v.z * wv.z * scale); o[3] = (__bf16)(v.w * wv.w * scale);
    *(bf16x4*)&h16[(size_t)row * DMODEL + t * 4] = o;
    *(bf16x4*)&hrev16[(size_t)(L_SEQ - 1 - row) * DMODEL + t * 4] = o;
}

// ---------------------------------------------------------------- causal depthwise conv (k=4) + silu
__global__ __launch_bounds__(256) void conv_silu_kernel(
    const float* __restrict__ xz, const float* __restrict__ w,
    const float* __restrict__ b, float* __restrict__ xc, __bf16* __restrict__ xc16)
{
    const int idx = blockIdx.x * 256 + threadIdx.x;   // over L*DINNER
    const int d = idx & (DINNER - 1);
    const int t = idx >> 11;
    float acc = b[d];
    const float4 wv = *(const float4*)(w + d * 4);
    const float wj[4] = {wv.x, wv.y, wv.z, wv.w};
    #pragma unroll
    for (int j = 0; j < 4; ++j) {
        const int tt = t - 3 + j;
        if (tt >= 0) acc += wj[j] * xz[(size_t)tt * ISIZE + d];
    }
    const float val = acc / (1.f + __expf(-acc));
    xc[(size_t)idx] = val;
    xc16[(size_t)idx] = (__bf16)val;
}

// ---------------------------------------------------------------- scan phase 1 (reg-state): per-chunk summaries
// one thread per (chunk c, channel d); all 16 n-states in registers.
__global__ __launch_bounds__(256) void scan_p1(
    const float* __restrict__ u, const float* __restrict__ dt,
    const float* __restrict__ dbc, const float* __restrict__ A_log,
    float* __restrict__ Pb, float* __restrict__ Sb)
{
    __shared__ float sB[TC * 16];
    const int tid = threadIdx.x;
    const int c = blockIdx.x;
    const int d = blockIdx.y * 256 + tid;
    const int t0 = c * TC;
    for (int i = tid; i < TC * 16; i += 256)
        sB[i] = dbc[(t0 + (i >> 4)) * DBC_LD + DTRANK + (i & 15)];
    __syncthreads();
    float A[16], h[16], Pa[16];
    #pragma unroll
    for (int n = 0; n < 16; n += 4) {
        const float4 av = *(const float4*)(A_log + (size_t)d * 16 + n);
        A[n]   = -__expf(av.x); A[n+1] = -__expf(av.y);
        A[n+2] = -__expf(av.z); A[n+3] = -__expf(av.w);
    }
    #pragma unroll
    for (int n = 0; n < 16; ++n) { h[n] = 0.f; Pa[n] = 1.f; }
    #pragma unroll 2
    for (int t = 0; t < TC; ++t) {
        const float dtv = dt[(size_t)(t0 + t) * DINNER + d];
        const float du  = dtv * u[(size_t)(t0 + t) * DINNER + d];
        #pragma unroll
        for (int n = 0; n < 16; ++n) {
            const float a = __expf(dtv * A[n]);
            h[n] = a * h[n] + du * sB[t * 16 + n];
            Pa[n] *= a;
        }
    }
    float* pp = Pb + ((size_t)c * DINNER + d) * 16;
    float* sp = Sb + ((size_t)c * DINNER + d) * 16;
    #pragma unroll
    for (int n = 0; n < 16; n += 4) {
        f32x4 pv = {Pa[n], Pa[n+1], Pa[n+2], Pa[n+3]};
        f32x4 sv = {h[n],  h[n+1],  h[n+2],  h[n+3]};
        *(f32x4*)(pp + n) = pv;
        *(f32x4*)(sp + n) = sv;
    }
}

// ---------------------------------------------------------------- scan phase 2: combine chunk states
__global__ __launch_bounds__(256) void scan_mid(
    const float* __restrict__ Pb, const float* __restrict__ Sb, float* __restrict__ Hinit)
{
    const int i = blockIdx.x * 256 + threadIdx.x;   // (d,n) index
    float H = 0.f;
    for (int c = 0; c < NC; ++c) {
        Hinit[(size_t)c * 32768 + i] = H;
        H = Pb[(size_t)c * 32768 + i] * H + Sb[(size_t)c * 32768 + i];
    }
}

// ---------------------------------------------------------------- scan phase 3 (reg-state): recompute + y + gate -> bf16
__global__ __launch_bounds__(256) void scan_p3(
    const float* __restrict__ u, const float* __restrict__ dt,
    const float* __restrict__ dbc, const float* __restrict__ A_log,
    const float* __restrict__ Dp, const float* __restrict__ Hinit,
    const float* __restrict__ z, __bf16* __restrict__ out16)
{
    __shared__ float sB[TC * 16], sC[TC * 16];
    const int tid = threadIdx.x;
    const int c = blockIdx.x;
    const int d = blockIdx.y * 256 + tid;
    const int t0 = c * TC;
    for (int i = tid; i < TC * 16; i += 256) {
        sB[i] = dbc[(t0 + (i >> 4)) * DBC_LD + DTRANK + (i & 15)];
        sC[i] = dbc[(t0 + (i >> 4)) * DBC_LD + DTRANK + DSTATE + (i & 15)];
    }
    __syncthreads();
    float A[16], h[16];
    const float* hp = Hinit + ((size_t)c * DINNER + d) * 16;
    #pragma unroll
    for (int n = 0; n < 16; n += 4) {
        const float4 av = *(const float4*)(A_log + (size_t)d * 16 + n);
        A[n]   = -__expf(av.x); A[n+1] = -__expf(av.y);
        A[n+2] = -__expf(av.z); A[n+3] = -__expf(av.w);
        const float4 hv = *(const float4*)(hp + n);
        h[n] = hv.x; h[n+1] = hv.y; h[n+2] = hv.z; h[n+3] = hv.w;
    }
    const float Dv = Dp[d];
    #pragma unroll 2
    for (int t = 0; t < TC; ++t) {
        const float dtv = dt[(size_t)(t0 + t) * DINNER + d];
        const float uv  = u[(size_t)(t0 + t) * DINNER + d];
        const float du  = dtv * uv;
        float y = uv * Dv;
        #pragma unroll
        for (int n = 0; n < 16; ++n) {
            const float a = __expf(dtv * A[n]);
            h[n] = a * h[n] + du * sB[t * 16 + n];
            y += h[n] * sC[t * 16 + n];
        }
        const float zv = z[(size_t)(t0 + t) * ISIZE + d];
        out16[(size_t)(t0 + t) * DINNER + d] = (__bf16)(y * (zv / (1.f + __expf(-zv))));
    }
}

// ---------------------------------------------------------------- x2 = x + rmsnorm(ysum)*mw ; h2_16 = bf16(rmsnorm(x2)*w2)
__global__ __launch_bounds__(256) void addnorm2_kernel(
    const float* __restrict__ x0, const float* __restrict__ ys,
    const float* __restrict__ mw, const float* __restrict__ w2,
    float* __restrict__ x2, __bf16* __restrict__ h2_16)
{
    __shared__ float sred[8];
    const int row = blockIdx.x, t = threadIdx.x;
    float4 yv = ((const float4*)(ys + (size_t)row * DMODEL))[t];
    float ss = yv.x*yv.x + yv.y*yv.y + yv.z*yv.z + yv.w*yv.w;
    #pragma unroll
    for (int m = 1; m < 64; m <<= 1) ss += __shfl_xor(ss, m);
    if ((t & 63) == 0) sred[t >> 6] = ss;
    __syncthreads();
    const float s1 = sred[0] + sred[1] + sred[2] + sred[3];
    const float sc1 = rsqrtf(s1 * (1.f / DMODEL) + 1e-6f);
    float4 xv = ((const float4*)(x0 + (size_t)row * DMODEL))[t];
    float4 mv = ((const float4*)mw)[t];
    float4 o;
    o.x = xv.x + mv.x * yv.x * sc1; o.y = xv.y + mv.y * yv.y * sc1;
    o.z = xv.z + mv.z * yv.z * sc1; o.w = xv.w + mv.w * yv.w * sc1;
    ((float4*)(x2 + (size_t)row * DMODEL))[t] = o;
    float s2 = o.x*o.x + o.y*o.y + o.z*o.z + o.w*o.w;
    #pragma unroll
    for (int m = 1; m < 64; m <<= 1) s2 += __shfl_xor(s2, m);
    if ((t & 63) == 0) sred[4 + (t >> 6)] = s2;
    __syncthreads();
    const float st = sred[4] + sred[5] + sred[6] + sred[7];
    const float sc2 = rsqrtf(st * (1.f / DMODEL) + 1e-6f);
    float4 wv = ((const float4*)w2)[t];
    bf16x4 o2;
    o2[0] = (__bf16)(wv.x * o.x * sc2); o2[1] = (__bf16)(wv.y * o.y * sc2);
    o2[2] = (__bf16)(wv.z * o.z * sc2); o2[3] = (__bf16)(wv.w * o.w * sc2);
    *(bf16x4*)&h2_16[(size_t)row * DMODEL + t * 4] = o2;
}

// ---------------------------------------------------------------- m16 = bf16(silu(g) * u)
__global__ __launch_bounds__(256) void silu_mul_kernel(
    const float* __restrict__ g, const float* __restrict__ u, __bf16* __restrict__ m16)
{
    const size_t i8 = ((size_t)blockIdx.x * 256 + threadIdx.x) * 8;
    const float4 g0 = *(const float4*)(g + i8), g1 = *(const float4*)(g + i8 + 4);
    const float4 u0 = *(const float4*)(u + i8), u1 = *(const float4*)(u + i8 + 4);
    bf16x8 o;
    o[0] = (__bf16)(g0.x / (1.f + __expf(-g0.x)) * u0.x);
    o[1] = (__bf16)(g0.y / (1.f + __expf(-g0.y)) * u0.y);
    o[2] = (__bf16)(g0.z / (1.f + __expf(-g0.z)) * u0.z);
    o[3] = (__bf16)(g0.w / (1.f + __expf(-g0.w)) * u0.w);
    o[4] = (__bf16)(g1.x / (1.f + __expf(-g1.x)) * u1.x);
    o[5] = (__bf16)(g1.y / (1.f + __expf(-g1.y)) * u1.y);
    o[6] = (__bf16)(g1.z / (1.f + __expf(-g1.z)) * u1.z);
    o[7] = (__bf16)(g1.w / (1.f + __expf(-g1.w)) * u1.w);
    *(bf16x8*)(m16 + i8) = o;
}

// ---------------------------------------------------------------- launch
extern "C" void kernel_launch(void* const* d_in, const int* in_sizes, int n_in,
                              void* d_out, int out_size, void* d_ws, size_t ws_size,
                              hipStream_t stream)
{
    const float* x       = (const float*)d_in[0];
    const float* mask    = (const float*)d_in[1];
    const float* mnorm_w = (const float*)d_in[2];
    const float* ln1_w   = (const float*)d_in[3];
    const float* ln2_w   = (const float*)d_in[4];
    const float* gate_w  = (const float*)d_in[5];
    const float* up_w    = (const float*)d_in[6];
    const float* down_w  = (const float*)d_in[7];
    const float* in_w[2]    = {(const float*)d_in[8],  (const float*)d_in[17]};
    const float* conv_w[2]  = {(const float*)d_in[9],  (const float*)d_in[18]};
    const float* conv_b[2]  = {(const float*)d_in[10], (const float*)d_in[19]};
    const float* xproj_w[2] = {(const float*)d_in[11], (const float*)d_in[20]};
    const float* dt_w[2]    = {(const float*)d_in[12], (const float*)d_in[21]};
    const float* dt_b[2]    = {(const float*)d_in[13], (const float*)d_in[22]};
    const float* A_log[2]   = {(const float*)d_in[14], (const float*)d_in[23]};
    const float* Dp[2]      = {(const float*)d_in[15], (const float*)d_in[24]};
    const float* out_w[2]   = {(const float*)d_in[16], (const float*)d_in[25]};

    float* ws = (float*)d_ws;
    const size_t MF = 1u << 20;                    // 1M floats
    __bf16* h16     = (__bf16*)(ws + 0 * MF);      // 2M bf16
    __bf16* hrev16  = (__bf16*)(ws + 1 * MF);      // 2M bf16
    float*  ysum    = ws + 2 * MF;                 // 2M f32
    float*  x2      = ws + 4 * MF;                 // 2M f32
    float*  xz      = ws + 6 * MF;                 // 8M f32 (also MLP gate out)
    float*  xc      = ws + 14 * MF;                // 4M f32 (with dtb: MLP up out)
    float*  dtb     = ws + 18 * MF;                // 4M f32
    __bf16* xc16    = (__bf16*)(ws + 22 * MF);     // 4M bf16
    __bf16* ygate16 = (__bf16*)(ws + 24 * MF);     // 4M bf16
    float*  dbc     = ws + 26 * MF;                // L*96 f32
    __bf16* dbc16   = (__bf16*)(ws + 26 * MF + 262144);  // L*64 bf16
    float*  Pb      = ws + 26 * MF + 524288;       // 2M f32   (scan phase only)
    float*  Sb      = ws + 28 * MF + 524288;       // 2M f32
    float*  Hinit   = ws + 30 * MF + 524288;       // 2M f32
    __bf16* h2_16   = (__bf16*)(ws + 26 * MF + 524288);  // reuse Pb post-scan, 2M bf16
    __bf16* mbuf16  = (__bf16*)(ws + 27 * MF + 524288);  // reuse, 8M bf16
    __bf16* wbase   = (__bf16*)(ws + 33 * MF);     // bf16 weights
    const size_t M4 = 4u << 20, M2 = 2u << 20;
    __bf16* wIN[2]  = {wbase,             wbase + M4};
    __bf16* wOUT[2] = {wbase + 2 * M4,    wbase + 2 * M4 + M2};
    __bf16* wG      = wbase + 3 * M4;
    __bf16* wU      = wbase + 4 * M4;
    __bf16* wDN     = wbase + 5 * M4;
    __bf16* wXP[2]  = {wbase + 6 * M4,            wbase + 6 * M4 + 196608};
    __bf16* wDT[2]  = {wbase + 6 * M4 + 393216,   wbase + 6 * M4 + 524288};

    // ---- weight conversion (single batched kernel)
    CvtJobs j;
    const float* srcs[NJOBS] = {in_w[0], in_w[1], out_w[0], out_w[1], gate_w, up_w, down_w,
                                xproj_w[0], xproj_w[1], dt_w[0], dt_w[1]};
    __bf16* dsts[NJOBS] = {wIN[0], wIN[1], wOUT[0], wOUT[1], wG, wU, wDN,
                           wXP[0], wXP[1], wDT[0], wDT[1]};
    const int szs[NJOBS] = {4194304, 4194304, 2097152, 2097152, 4194304, 4194304, 4194304,
                            196608, 196608, 131072, 131072};
    int cum = 0;
    for (int i = 0; i < NJOBS; ++i) {
        j.src[i] = srcs[i]; j.dst[i] = dsts[i]; j.cum[i] = cum; cum += szs[i] / 8;
    }
    j.cum[NJOBS] = cum;
    cvt_multi<<<(cum + 255) / 256, 256, 0, stream>>>(j, cum);

    rmsnorm_mask_kernel<<<L_SEQ, 256, 0, stream>>>(x, ln1_w, mask, h16, hrev16);

    for (int dir = 0; dir < 2; ++dir) {
        const __bf16* hd = dir ? hrev16 : h16;
        // xz = h @ in_w^T            (2048 x 4096, K=1024)
        gemm16<0><<<dim3(16, 32), 256, 0, stream>>>(
            hd, wIN[dir], xz, nullptr, nullptr, 2048, 4096, 1024, 1024, 1024, 4096);
        // xc = silu(causal_conv(xi)), dual f32+bf16
        conv_silu_kernel<<<(L_SEQ * DINNER) / 256, 256, 0, stream>>>(
            xz, conv_w[dir], conv_b[dir], xc, xc16);
        // dbc = xc @ xproj^T         (2048 x 96, K=2048), + bf16 dup of dt_raw cols
        gemm16<4><<<dim3(16, 1), 256, 0, stream>>>(
            xc16, wXP[dir], dbc, nullptr, dbc16, 2048, 96, 2048, 2048, 2048, 96);
        // dt = softplus(dt_raw @ dt_w^T + dt_b)   (2048 x 2048, K=64)
        gemm16<1><<<dim3(16, 16), 256, 0, stream>>>(
            dbc16, wDT[dir], dtb, dt_b[dir], nullptr, 2048, 2048, 64, 64, 64, 2048);
        // chunk-parallel selective scan (register-state) + Dp skip + silu(z) gating -> bf16
        scan_p1<<<dim3(NC, DINNER / 256), 256, 0, stream>>>(
            xc, dtb, dbc, A_log[dir], Pb, Sb);
        scan_mid<<<(DINNER * DSTATE) / 256, 256, 0, stream>>>(Pb, Sb, Hinit);
        scan_p3<<<dim3(NC, DINNER / 256), 256, 0, stream>>>(
            xc, dtb, dbc, A_log[dir], Dp[dir], Hinit, xz + DINNER, ygate16);
        // out-proj (fwd: store; bwd: accumulate with row flip)
        if (dir == 0)
            gemm16<0><<<dim3(16, 8), 256, 0, stream>>>(
                ygate16, wOUT[0], ysum, nullptr, nullptr, 2048, 1024, 2048, 2048, 2048, 1024);
        else
            gemm16<2><<<dim3(16, 8), 256, 0, stream>>>(
                ygate16, wOUT[1], ysum, nullptr, nullptr, 2048, 1024, 2048, 2048, 2048, 1024);
    }

    // x2 = x + rmsnorm(ysum)*mnorm_w ; h2_16 = bf16(rmsnorm(x2)*ln2_w)
    addnorm2_kernel<<<L_SEQ, 256, 0, stream>>>(x, ysum, mnorm_w, ln2_w, x2, h2_16);

    // MLP
    gemm16<0><<<dim3(16, 32), 256, 0, stream>>>(
        h2_16, wG, xz, nullptr, nullptr, 2048, 4096, 1024, 1024, 1024, 4096);
    gemm16<0><<<dim3(16, 32), 256, 0, stream>>>(
        h2_16, wU, xc, nullptr, nullptr, 2048, 4096, 1024, 1024, 1024, 4096);
    silu_mul_kernel<<<(L_SEQ * ISIZE) / (256 * 8), 256, 0, stream>>>(xz, xc, mbuf16);
    gemm16<3><<<dim3(16, 8), 256, 0, stream>>>(
        mbuf16, wDN, (float*)d_out, x2, nullptr, 2048, 1024, 4096, 4096, 4096, 1024);
}

// Round 5
// 439.703 us; speedup vs baseline: 8.9041x; 1.3992x over previous
//
#include <hip/hip_runtime.h>

#define L_SEQ 2048
#define DMODEL 1024
#define DINNER 2048
#define DSTATE 16
#define DTRANK 64
#define DBC_LD 96
#define ISIZE 4096
#define NC 64   // scan chunks
#define TC 32   // timesteps per chunk
#define YGLD 4096

typedef __bf16 bf16x8 __attribute__((ext_vector_type(8)));
typedef __bf16 bf16x4 __attribute__((ext_vector_type(4)));
typedef float f32x4 __attribute__((ext_vector_type(4)));

__device__ __forceinline__ void gload_lds16(const void* g, void* l) {
    __builtin_amdgcn_global_load_lds(
        (const __attribute__((address_space(1))) void*)g,
        (__attribute__((address_space(3))) void*)l, 16, 0, 0);
}

// ---------------------------------------------------------------- bf16 GEMM NT
// C[r][c] = sum_k A[r][k]*W[c][k]; 128x128 tile, 4 waves, BK=64, gload_lds + XOR swizzle.
// Supports K-split via blockIdx.z (kSplit parts, each K/kSplit long).
// EPI: 0=store, 1=softplus(acc+aux[c]), 5=partial store to C + kz*M*ldc
template<int EPI>
__global__ __launch_bounds__(256) void gemm16(
    const __bf16* __restrict__ A, const __bf16* __restrict__ W,
    float* __restrict__ C, const float* __restrict__ aux,
    int M, int N, int K, int lda, int ldb, int ldc, int kSplit)
{
    __shared__ __bf16 lsA[128 * 64];
    __shared__ __bf16 lsB[128 * 64];
    const int tid  = threadIdx.x;
    const int lane = tid & 63;
    const int wave = tid >> 6;
    const int wr = wave >> 1, wc = wave & 1;
    const int m0 = blockIdx.x * 128, n0 = blockIdx.y * 128;
    const int kz = blockIdx.z;
    const int Kc = K / kSplit;
    const int q  = lane & 7;
    const int rb = wave * 32 + (lane >> 3);

    f32x4 acc[4][4] = {};

    for (int k0 = kz * Kc; k0 < kz * Kc + Kc; k0 += 64) {
        #pragma unroll
        for (int i = 0; i < 4; ++i) {
            const int row = rb + i * 8;
            const int sk  = (q * 8) ^ ((row & 7) << 3);
            gload_lds16(A + (size_t)(m0 + row) * lda + k0 + sk,
                        &lsA[(wave * 4 + i) * 512]);
            int rw = n0 + row; rw = rw < N ? rw : N - 1;
            gload_lds16(W + (size_t)rw * ldb + k0 + sk,
                        &lsB[(wave * 4 + i) * 512]);
        }
        __syncthreads();
        #pragma unroll
        for (int kk = 0; kk < 2; ++kk) {
            bf16x8 af[4], bf[4];
            #pragma unroll
            for (int m = 0; m < 4; ++m) {
                const int row = wr * 64 + m * 16 + (lane & 15);
                const int kb  = (kk * 32 + (lane >> 4) * 8) ^ ((row & 7) << 3);
                af[m] = *(const bf16x8*)&lsA[row * 64 + kb];
            }
            #pragma unroll
            for (int n = 0; n < 4; ++n) {
                const int row = wc * 64 + n * 16 + (lane & 15);
                const int kb  = (kk * 32 + (lane >> 4) * 8) ^ ((row & 7) << 3);
                bf[n] = *(const bf16x8*)&lsB[row * 64 + kb];
            }
            #pragma unroll
            for (int m = 0; m < 4; ++m)
            #pragma unroll
            for (int n = 0; n < 4; ++n)
                acc[m][n] = __builtin_amdgcn_mfma_f32_16x16x32_bf16(af[m], bf[n], acc[m][n], 0, 0, 0);
        }
        __syncthreads();
    }

    float* Cout = (EPI == 5) ? C + (size_t)kz * M * ldc : C;
    const int cr = (lane >> 4) * 4, cc = lane & 15;
    #pragma unroll
    for (int mi = 0; mi < 4; ++mi)
    #pragma unroll
    for (int ni = 0; ni < 4; ++ni) {
        const int c = n0 + wc * 64 + ni * 16 + cc;
        if (c >= N) continue;
        #pragma unroll
        for (int g = 0; g < 4; ++g) {
            const int r = m0 + wr * 64 + mi * 16 + cr + g;
            float v = acc[mi][ni][g];
            if (EPI == 1) {
                float xv = v + aux[c];
                Cout[(size_t)r * ldc + c] = (xv > 20.f) ? xv : log1pf(__expf(xv));
            } else {
                Cout[(size_t)r * ldc + c] = v;
            }
        }
    }
}

// ---------------------------------------------------------------- fused gate/up MLP GEMM
// B-tile rows 0..63 = gate_w[n0..n0+63], rows 64..127 = up_w[n0..n0+63].
// Epilogue: m16[r][c] = bf16(silu(g)*u). Grid (M/128, N/64).
__global__ __launch_bounds__(256) void gemm_mlp(
    const __bf16* __restrict__ A, const __bf16* __restrict__ Wg,
    const __bf16* __restrict__ Wu, __bf16* __restrict__ m16,
    int M, int N, int K, int lda, int ldb, int ldm)
{
    __shared__ __bf16 lsA[128 * 64];
    __shared__ __bf16 lsB[128 * 64];
    const int tid  = threadIdx.x;
    const int lane = tid & 63;
    const int wave = tid >> 6;
    const int wr = wave >> 1, wc = wave & 1;
    const int m0 = blockIdx.x * 128, n0 = blockIdx.y * 64;
    const int q  = lane & 7;
    const int rb = wave * 32 + (lane >> 3);

    f32x4 acc[4][4] = {};

    for (int k0 = 0; k0 < K; k0 += 64) {
        #pragma unroll
        for (int i = 0; i < 4; ++i) {
            const int row = rb + i * 8;
            const int sk  = (q * 8) ^ ((row & 7) << 3);
            gload_lds16(A + (size_t)(m0 + row) * lda + k0 + sk,
                        &lsA[(wave * 4 + i) * 512]);
            const __bf16* src = (row < 64) ? Wg + (size_t)(n0 + row) * ldb
                                           : Wu + (size_t)(n0 + row - 64) * ldb;
            gload_lds16(src + k0 + sk, &lsB[(wave * 4 + i) * 512]);
        }
        __syncthreads();
        #pragma unroll
        for (int kk = 0; kk < 2; ++kk) {
            bf16x8 af[4], bf[4];
            #pragma unroll
            for (int m = 0; m < 4; ++m) {
                const int row = wr * 64 + m * 16 + (lane & 15);
                const int kb  = (kk * 32 + (lane >> 4) * 8) ^ ((row & 7) << 3);
                af[m] = *(const bf16x8*)&lsA[row * 64 + kb];
            }
            #pragma unroll
            for (int n = 0; n < 4; ++n) {
                const int row = wc * 32 + (n & 1) * 16 + (n >> 1) * 64 + (lane & 15);
                const int kb  = (kk * 32 + (lane >> 4) * 8) ^ ((row & 7) << 3);
                bf[n] = *(const bf16x8*)&lsB[row * 64 + kb];
            }
            #pragma unroll
            for (int m = 0; m < 4; ++m)
            #pragma unroll
            for (int n = 0; n < 4; ++n)
                acc[m][n] = __builtin_amdgcn_mfma_f32_16x16x32_bf16(af[m], bf[n], acc[m][n], 0, 0, 0);
        }
        __syncthreads();
    }

    const int cr = (lane >> 4) * 4, cc = lane & 15;
    #pragma unroll
    for (int mi = 0; mi < 4; ++mi)
    #pragma unroll
    for (int nn = 0; nn < 2; ++nn) {
        const int c = n0 + wc * 32 + nn * 16 + cc;
        #pragma unroll
        for (int g = 0; g < 4; ++g) {
            const int r = m0 + wr * 64 + mi * 16 + cr + g;
            const float gv = acc[mi][nn][g];
            const float uv = acc[mi][nn + 2][g];
            m16[(size_t)r * ldm + c] = (__bf16)(gv / (1.f + __expf(-gv)) * uv);
        }
    }
}

// ---------------------------------------------------------------- batched f32 -> bf16 weight convert
#define NJOBS 9
struct CvtJobs {
    const float* src[NJOBS];
    __bf16* dst[NJOBS];
    int cum[NJOBS + 1];   // prefix sums, units of 8 elems
};
__global__ __launch_bounds__(256) void cvt_multi(CvtJobs j, int total8) {
    const int g = blockIdx.x * 256 + threadIdx.x;
    if (g >= total8) return;
    for (int i = 0; i < NJOBS; ++i) {
        if (g < j.cum[i + 1]) {
            const int off = (g - j.cum[i]) * 8;
            const float4 a = *(const float4*)(j.src[i] + off);
            const float4 b = *(const float4*)(j.src[i] + off + 4);
            bf16x8 o;
            o[0]=(__bf16)a.x; o[1]=(__bf16)a.y; o[2]=(__bf16)a.z; o[3]=(__bf16)a.w;
            o[4]=(__bf16)b.x; o[5]=(__bf16)b.y; o[6]=(__bf16)b.z; o[7]=(__bf16)b.w;
            *(bf16x8*)(j.dst[i] + off) = o;
            return;
        }
    }
}

// out_w_f/out_w_b (1024 x 2048 f32 each) -> wOUTcat (1024 x 4096 bf16, f|b)
__global__ __launch_bounds__(256) void cvt_outw(
    const float* __restrict__ wf, const float* __restrict__ wb, __bf16* __restrict__ dst)
{
    const int g = blockIdx.x * 256 + threadIdx.x;      // over 2*1024*2048/8
    const int half = g >> 18;                          // 262144 groups per half
    const int i = (g & 262143) * 8;
    const int r = i >> 11, c = i & 2047;
    const float* src = (half ? wb : wf) + (size_t)r * 2048 + c;
    const float4 a = *(const float4*)src;
    const float4 b = *(const float4*)(src + 4);
    bf16x8 o;
    o[0]=(__bf16)a.x; o[1]=(__bf16)a.y; o[2]=(__bf16)a.z; o[3]=(__bf16)a.w;
    o[4]=(__bf16)b.x; o[5]=(__bf16)b.y; o[6]=(__bf16)b.z; o[7]=(__bf16)b.w;
    *(bf16x8*)(dst + (size_t)r * 4096 + half * 2048 + c) = o;
}

// ---------------------------------------------------------------- rmsnorm1 (+mask) -> bf16 h + flipped bf16 h
__global__ __launch_bounds__(256) void rmsnorm_mask_kernel(
    const float* __restrict__ x, const float* __restrict__ w, const float* __restrict__ mask,
    __bf16* __restrict__ h16, __bf16* __restrict__ hrev16)
{
    __shared__ float sred[4];
    const int row = blockIdx.x, t = threadIdx.x;
    float4 v = ((const float4*)(x + (size_t)row * DMODEL))[t];
    float ss = v.x*v.x + v.y*v.y + v.z*v.z + v.w*v.w;
    #pragma unroll
    for (int m = 1; m < 64; m <<= 1) ss += __shfl_xor(ss, m);
    if ((t & 63) == 0) sred[t >> 6] = ss;
    __syncthreads();
    ss = sred[0] + sred[1] + sred[2] + sred[3];
    const float scale = rsqrtf(ss * (1.f / DMODEL) + 1e-6f) * mask[row];
    float4 wv = ((const float4*)w)[t];
    bf16x4 o;
    o[0] = (__bf16)(v.x * wv.x * scale); o[1] = (__bf16)(v.y * wv.y * scale);
    o[2] = (__bf16)(v.z * wv.z * scale); o[3] = (__bf16)(v.w * wv.w * scale);
    *(bf16x4*)&h16[(size_t)row * DMODEL + t * 4] = o;
    *(bf16x4*)&hrev16[(size_t)(L_SEQ - 1 - row) * DMODEL + t * 4] = o;
}

// ---------------------------------------------------------------- causal depthwise conv (k=4) + silu
__global__ __launch_bounds__(256) void conv_silu_kernel(
    const float* __restrict__ xz, const float* __restrict__ w,
    const float* __restrict__ b, float* __restrict__ xc, __bf16* __restrict__ xc16)
{
    const int idx = blockIdx.x * 256 + threadIdx.x;   // over L*DINNER
    const int d = idx & (DINNER - 1);
    const int t = idx >> 11;
    float acc = b[d];
    const float4 wv = *(const float4*)(w + d * 4);
    const float wj[4] = {wv.x, wv.y, wv.z, wv.w};
    #pragma unroll
    for (int j = 0; j < 4; ++j) {
        const int tt = t - 3 + j;
        if (tt >= 0) acc += wj[j] * xz[(size_t)tt * ISIZE + d];
    }
    const float val = acc / (1.f + __expf(-acc));
    xc[(size_t)idx] = val;
    xc16[(size_t)idx] = (__bf16)val;
}

// ---------------------------------------------------------------- dbc finalize: sum 8 xproj K-partials
__global__ __launch_bounds__(256) void dbc_finalize(
    const float* __restrict__ P, float* __restrict__ dbc, __bf16* __restrict__ dbc16)
{
    const int i = blockIdx.x * 256 + threadIdx.x;     // over 2048*96
    float v = 0.f;
    #pragma unroll
    for (int s = 0; s < 8; ++s) v += P[(size_t)s * (L_SEQ * DBC_LD) + i];
    dbc[i] = v;
    const int r = i / 96, c = i - r * 96;
    if (c < DTRANK) dbc16[(size_t)r * DTRANK + c] = (__bf16)v;
}

// ---------------------------------------------------------------- scan phase 1 (reg-state)
__global__ __launch_bounds__(256) void scan_p1(
    const float* __restrict__ u, const float* __restrict__ dt,
    const float* __restrict__ dbc, const float* __restrict__ A_log,
    float* __restrict__ Pb, float* __restrict__ Sb)
{
    __shared__ float sB[TC * 16];
    const int tid = threadIdx.x;
    const int c = blockIdx.x;
    const int d = blockIdx.y * 256 + tid;
    const int t0 = c * TC;
    for (int i = tid; i < TC * 16; i += 256)
        sB[i] = dbc[(t0 + (i >> 4)) * DBC_LD + DTRANK + (i & 15)];
    __syncthreads();
    float A[16], h[16], Pa[16];
    #pragma unroll
    for (int n = 0; n < 16; n += 4) {
        const float4 av = *(const float4*)(A_log + (size_t)d * 16 + n);
        A[n]   = -__expf(av.x); A[n+1] = -__expf(av.y);
        A[n+2] = -__expf(av.z); A[n+3] = -__expf(av.w);
    }
    #pragma unroll
    for (int n = 0; n < 16; ++n) { h[n] = 0.f; Pa[n] = 1.f; }
    #pragma unroll 2
    for (int t = 0; t < TC; ++t) {
        const float dtv = dt[(size_t)(t0 + t) * DINNER + d];
        const float du  = dtv * u[(size_t)(t0 + t) * DINNER + d];
        #pragma unroll
        for (int n = 0; n < 16; ++n) {
            const float a = __expf(dtv * A[n]);
            h[n] = a * h[n] + du * sB[t * 16 + n];
            Pa[n] *= a;
        }
    }
    float* pp = Pb + ((size_t)c * DINNER + d) * 16;
    float* sp = Sb + ((size_t)c * DINNER + d) * 16;
    #pragma unroll
    for (int n = 0; n < 16; n += 4) {
        f32x4 pv = {Pa[n], Pa[n+1], Pa[n+2], Pa[n+3]};
        f32x4 sv = {h[n],  h[n+1],  h[n+2],  h[n+3]};
        *(f32x4*)(pp + n) = pv;
        *(f32x4*)(sp + n) = sv;
    }
}

// ---------------------------------------------------------------- scan phase 2: combine chunk states
__global__ __launch_bounds__(256) void scan_mid(
    const float* __restrict__ Pb, const float* __restrict__ Sb, float* __restrict__ Hinit)
{
    const int i = blockIdx.x * 256 + threadIdx.x;
    float H = 0.f;
    for (int c = 0; c < NC; ++c) {
        Hinit[(size_t)c * 32768 + i] = H;
        H = Pb[(size_t)c * 32768 + i] * H + Sb[(size_t)c * 32768 + i];
    }
}

// ---------------------------------------------------------------- scan phase 3: recompute + y + gate -> bf16 (to ygcat)
__global__ __launch_bounds__(256) void scan_p3(
    const float* __restrict__ u, const float* __restrict__ dt,
    const float* __restrict__ dbc, const float* __restrict__ A_log,
    const float* __restrict__ Dp, const float* __restrict__ Hinit,
    const float* __restrict__ z, __bf16* __restrict__ out16,
    int flip, int coloff)
{
    __shared__ float sB[TC * 16], sC[TC * 16];
    const int tid = threadIdx.x;
    const int c = blockIdx.x;
    const int d = blockIdx.y * 256 + tid;
    const int t0 = c * TC;
    for (int i = tid; i < TC * 16; i += 256) {
        sB[i] = dbc[(t0 + (i >> 4)) * DBC_LD + DTRANK + (i & 15)];
        sC[i] = dbc[(t0 + (i >> 4)) * DBC_LD + DTRANK + DSTATE + (i & 15)];
    }
    __syncthreads();
    float A[16], h[16];
    const float* hp = Hinit + ((size_t)c * DINNER + d) * 16;
    #pragma unroll
    for (int n = 0; n < 16; n += 4) {
        const float4 av = *(const float4*)(A_log + (size_t)d * 16 + n);
        A[n]   = -__expf(av.x); A[n+1] = -__expf(av.y);
        A[n+2] = -__expf(av.z); A[n+3] = -__expf(av.w);
        const float4 hv = *(const float4*)(hp + n);
        h[n] = hv.x; h[n+1] = hv.y; h[n+2] = hv.z; h[n+3] = hv.w;
    }
    const float Dv = Dp[d];
    #pragma unroll 2
    for (int t = 0; t < TC; ++t) {
        const float dtv = dt[(size_t)(t0 + t) * DINNER + d];
        const float uv  = u[(size_t)(t0 + t) * DINNER + d];
        const float du  = dtv * uv;
        float y = uv * Dv;
        #pragma unroll
        for (int n = 0; n < 16; ++n) {
            const float a = __expf(dtv * A[n]);
            h[n] = a * h[n] + du * sB[t * 16 + n];
            y += h[n] * sC[t * 16 + n];
        }
        const float zv = z[(size_t)(t0 + t) * ISIZE + d];
        const int orow = flip ? (L_SEQ - 1 - (t0 + t)) : (t0 + t);
        out16[(size_t)orow * YGLD + coloff + d] = (__bf16)(y * (zv / (1.f + __expf(-zv))));
    }
}

// ---------------------------------------------------------------- x2 = x + rmsnorm(sum P0..3)*mw ; h2_16 = bf16(rmsnorm(x2)*w2)
__global__ __launch_bounds__(256) void addnorm2_kernel(
    const float* __restrict__ x0, const float* __restrict__ P,
    const float* __restrict__ mw, const float* __restrict__ w2,
    float* __restrict__ x2, __bf16* __restrict__ h2_16)
{
    __shared__ float sred[8];
    const int row = blockIdx.x, t = threadIdx.x;
    const size_t PS = (size_t)L_SEQ * DMODEL;
    float4 yv = ((const float4*)(P + (size_t)row * DMODEL))[t];
    #pragma unroll
    for (int s = 1; s < 4; ++s) {
        float4 pv = ((const float4*)(P + s * PS + (size_t)row * DMODEL))[t];
        yv.x += pv.x; yv.y += pv.y; yv.z += pv.z; yv.w += pv.w;
    }
    float ss = yv.x*yv.x + yv.y*yv.y + yv.z*yv.z + yv.w*yv.w;
    #pragma unroll
    for (int m = 1; m < 64; m <<= 1) ss += __shfl_xor(ss, m);
    if ((t & 63) == 0) sred[t >> 6] = ss;
    __syncthreads();
    const float s1 = sred[0] + sred[1] + sred[2] + sred[3];
    const float sc1 = rsqrtf(s1 * (1.f / DMODEL) + 1e-6f);
    float4 xv = ((const float4*)(x0 + (size_t)row * DMODEL))[t];
    float4 mv = ((const float4*)mw)[t];
    float4 o;
    o.x = xv.x + mv.x * yv.x * sc1; o.y = xv.y + mv.y * yv.y * sc1;
    o.z = xv.z + mv.z * yv.z * sc1; o.w = xv.w + mv.w * yv.w * sc1;
    ((float4*)(x2 + (size_t)row * DMODEL))[t] = o;
    float s2 = o.x*o.x + o.y*o.y + o.z*o.z + o.w*o.w;
    #pragma unroll
    for (int m = 1; m < 64; m <<= 1) s2 += __shfl_xor(s2, m);
    if ((t & 63) == 0) sred[4 + (t >> 6)] = s2;
    __syncthreads();
    const float st = sred[4] + sred[5] + sred[6] + sred[7];
    const float sc2 = rsqrtf(st * (1.f / DMODEL) + 1e-6f);
    float4 wv = ((const float4*)w2)[t];
    bf16x4 o2;
    o2[0] = (__bf16)(wv.x * o.x * sc2); o2[1] = (__bf16)(wv.y * o.y * sc2);
    o2[2] = (__bf16)(wv.z * o.z * sc2); o2[3] = (__bf16)(wv.w * o.w * sc2);
    *(bf16x4*)&h2_16[(size_t)row * DMODEL + t * 4] = o2;
}

// ---------------------------------------------------------------- d_out = x2 + sum P0..3
__global__ __launch_bounds__(256) void addout_kernel(
    const float* __restrict__ x2, const float* __restrict__ P, float* __restrict__ out)
{
    const size_t i = ((size_t)blockIdx.x * 256 + threadIdx.x) * 4;
    const size_t PS = (size_t)L_SEQ * DMODEL;
    float4 v = *(const float4*)(x2 + i);
    #pragma unroll
    for (int s = 0; s < 4; ++s) {
        const float4 pv = *(const float4*)(P + s * PS + i);
        v.x += pv.x; v.y += pv.y; v.z += pv.z; v.w += pv.w;
    }
    *(float4*)(out + i) = v;
}

// ---------------------------------------------------------------- launch
extern "C" void kernel_launch(void* const* d_in, const int* in_sizes, int n_in,
                              void* d_out, int out_size, void* d_ws, size_t ws_size,
                              hipStream_t stream)
{
    const float* x       = (const float*)d_in[0];
    const float* mask    = (const float*)d_in[1];
    const float* mnorm_w = (const float*)d_in[2];
    const float* ln1_w   = (const float*)d_in[3];
    const float* ln2_w   = (const float*)d_in[4];
    const float* gate_w  = (const float*)d_in[5];
    const float* up_w    = (const float*)d_in[6];
    const float* down_w  = (const float*)d_in[7];
    const float* in_w[2]    = {(const float*)d_in[8],  (const float*)d_in[17]};
    const float* conv_w[2]  = {(const float*)d_in[9],  (const float*)d_in[18]};
    const float* conv_b[2]  = {(const float*)d_in[10], (const float*)d_in[19]};
    const float* xproj_w[2] = {(const float*)d_in[11], (const float*)d_in[20]};
    const float* dt_w[2]    = {(const float*)d_in[12], (const float*)d_in[21]};
    const float* dt_b[2]    = {(const float*)d_in[13], (const float*)d_in[22]};
    const float* A_log[2]   = {(const float*)d_in[14], (const float*)d_in[23]};
    const float* Dp[2]      = {(const float*)d_in[15], (const float*)d_in[24]};
    const float* out_w[2]   = {(const float*)d_in[16], (const float*)d_in[25]};

    float* ws = (float*)d_ws;
    const size_t MF = 1u << 20;                    // 1M floats = 4MB
    __bf16* h16     = (__bf16*)(ws + 0 * MF);      // 4MB
    __bf16* hrev16  = (__bf16*)(ws + 1 * MF);      // 4MB
    float*  x2      = ws + 2 * MF;                 // 8MB
    float*  xz      = ws + 4 * MF;                 // 32MB: per-dir xz; later out/down K-partials
    float*  xc      = ws + 12 * MF;                // 16MB f32 (scan u)
    float*  dtb     = ws + 16 * MF;                // 16MB f32
    __bf16* xc16    = (__bf16*)(ws + 20 * MF);     // 8MB
    __bf16* ygcat   = (__bf16*)(ws + 22 * MF);     // 16MB: [yg_f | yg_b_flip], ld 4096; later mbuf16
    float*  dbc     = ws + 26 * MF;                // 768KB
    __bf16* dbc16   = (__bf16*)(ws + 26 * MF + 262144);  // 256KB
    float*  dbcP    = ws + 27 * MF;                // 8 x 768KB = 6.3MB xproj partials
    float*  Pb      = ws + 29 * MF;                // 8MB
    float*  Sb      = ws + 31 * MF;                // 8MB
    float*  Hinit   = ws + 33 * MF;                // 8MB
    __bf16* h2_16   = (__bf16*)(ws + 35 * MF);     // 4MB
    __bf16* wbase   = (__bf16*)(ws + 36 * MF);
    const size_t M4 = 4u << 20;
    __bf16* wIN[2]  = {wbase, wbase + M4};
    __bf16* wOUTcat = wbase + 2 * M4;              // 1024 x 4096
    __bf16* wG      = wbase + 3 * M4;
    __bf16* wU      = wbase + 4 * M4;
    __bf16* wDN     = wbase + 5 * M4;
    __bf16* wXP[2]  = {wbase + 6 * M4,            wbase + 6 * M4 + 196608};
    __bf16* wDT[2]  = {wbase + 6 * M4 + 393216,   wbase + 6 * M4 + 524288};
    __bf16* mbuf16  = ygcat;                       // MLP intermediate reuses ygcat
    float*  gemmP   = xz;                          // 4 x 8MB K-split partials

    // ---- weight conversion
    CvtJobs j;
    const float* srcs[NJOBS] = {in_w[0], in_w[1], gate_w, up_w, down_w,
                                xproj_w[0], xproj_w[1], dt_w[0], dt_w[1]};
    __bf16* dsts[NJOBS] = {wIN[0], wIN[1], wG, wU, wDN, wXP[0], wXP[1], wDT[0], wDT[1]};
    const int szs[NJOBS] = {4194304, 4194304, 4194304, 4194304, 4194304,
                            196608, 196608, 131072, 131072};
    int cum = 0;
    for (int i = 0; i < NJOBS; ++i) {
        j.src[i] = srcs[i]; j.dst[i] = dsts[i]; j.cum[i] = cum; cum += szs[i] / 8;
    }
    j.cum[NJOBS] = cum;
    cvt_multi<<<(cum + 255) / 256, 256, 0, stream>>>(j, cum);
    cvt_outw<<<(2 * 1024 * 2048 / 8) / 256, 256, 0, stream>>>(out_w[0], out_w[1], wOUTcat);

    rmsnorm_mask_kernel<<<L_SEQ, 256, 0, stream>>>(x, ln1_w, mask, h16, hrev16);

    for (int dir = 0; dir < 2; ++dir) {
        const __bf16* hd = dir ? hrev16 : h16;
        // xz = h @ in_w^T            (2048 x 4096, K=1024)
        gemm16<0><<<dim3(16, 32), 256, 0, stream>>>(
            hd, wIN[dir], xz, nullptr, 2048, 4096, 1024, 1024, 1024, 4096, 1);
        // xc = silu(causal_conv(xi))
        conv_silu_kernel<<<(L_SEQ * DINNER) / 256, 256, 0, stream>>>(
            xz, conv_w[dir], conv_b[dir], xc, xc16);
        // dbc partials = xc @ xproj^T (2048 x 96, K=2048, split 8)
        gemm16<5><<<dim3(16, 1, 8), 256, 0, stream>>>(
            xc16, wXP[dir], dbcP, nullptr, 2048, 96, 2048, 2048, 2048, 96, 8);
        dbc_finalize<<<(L_SEQ * DBC_LD) / 256, 256, 0, stream>>>(dbcP, dbc, dbc16);
        // dt = softplus(dt_raw @ dt_w^T + dt_b)   (2048 x 2048, K=64)
        gemm16<1><<<dim3(16, 16), 256, 0, stream>>>(
            dbc16, wDT[dir], dtb, dt_b[dir], 2048, 2048, 64, 64, 64, 2048, 1);
        // chunk-parallel selective scan -> ygcat column block (dir1 time-flipped)
        scan_p1<<<dim3(NC, DINNER / 256), 256, 0, stream>>>(
            xc, dtb, dbc, A_log[dir], Pb, Sb);
        scan_mid<<<(DINNER * DSTATE) / 256, 256, 0, stream>>>(Pb, Sb, Hinit);
        scan_p3<<<dim3(NC, DINNER / 256), 256, 0, stream>>>(
            xc, dtb, dbc, A_log[dir], Dp[dir], Hinit, xz + DINNER, ygcat,
            dir, dir * DINNER);
    }

    // fused out-proj: ysum partials = ygcat @ wOUTcat^T  (2048 x 1024, K=4096, split 4)
    gemm16<5><<<dim3(16, 8, 4), 256, 0, stream>>>(
        ygcat, wOUTcat, gemmP, nullptr, 2048, 1024, 4096, 4096, 4096, 1024, 4);
    // x2 = x + rmsnorm(sum P)*mnorm_w ; h2_16 = bf16(rmsnorm(x2)*ln2_w)
    addnorm2_kernel<<<L_SEQ, 256, 0, stream>>>(x, gemmP, mnorm_w, ln2_w, x2, h2_16);

    // MLP: fused gate/up -> mbuf16 = bf16(silu(h2@Wg^T) * (h2@Wu^T))
    gemm_mlp<<<dim3(16, 64), 256, 0, stream>>>(
        h2_16, wG, wU, mbuf16, 2048, 4096, 1024, 1024, 1024, 4096);
    // down-proj partials (2048 x 1024, K=4096, split 4)
    gemm16<5><<<dim3(16, 8, 4), 256, 0, stream>>>(
        mbuf16, wDN, gemmP, nullptr, 2048, 1024, 4096, 4096, 4096, 1024, 4);
    // d_out = x2 + sum P
    addout_kernel<<<(L_SEQ * DMODEL) / (256 * 4), 256, 0, stream>>>(
        x2, gemmP, (float*)d_out);
}

// Round 6
// 384.011 us; speedup vs baseline: 10.1955x; 1.1450x over previous
//
#include <hip/hip_runtime.h>

#define L_SEQ 2048
#define DMODEL 1024
#define DINNER 2048
#define DSTATE 16
#define DTRANK 64
#define DBC_LD 96
#define NC 64   // scan chunks
#define TC 32   // timesteps per chunk
#define DCAT 4096          // both dirs' channels
#define XZLD 8192          // xzcat row stride
#define LS96 (L_SEQ * 96)

typedef __bf16 bf16x8 __attribute__((ext_vector_type(8)));
typedef __bf16 bf16x4 __attribute__((ext_vector_type(4)));
typedef float f32x4 __attribute__((ext_vector_type(4)));

__device__ __forceinline__ void gload_lds16(const void* g, void* l) {
    __builtin_amdgcn_global_load_lds(
        (const __attribute__((address_space(1))) void*)g,
        (__attribute__((address_space(3))) void*)l, 16, 0, 0);
}

// ---------------------------------------------------------------- bf16 GEMM NT
// C[r][c] = sum_k A[r][k]*W[c][k]; 128x128 tile, 4 waves, BK=64, gload_lds + XOR swizzle.
// EPI: 0=store f32, 1=softplus(acc+aux[c]), 5=partial store to C + kz*M*ldc,
//      6=bf16 store to Cb with row-flip for cols >= N/2 (fused bidirectional in-proj)
template<int EPI>
__global__ __launch_bounds__(256) void gemm16(
    const __bf16* __restrict__ A, const __bf16* __restrict__ W,
    float* __restrict__ C, const float* __restrict__ aux, __bf16* __restrict__ Cb,
    int M, int N, int K, int lda, int ldb, int ldc, int kSplit)
{
    __shared__ __bf16 lsA[128 * 64];
    __shared__ __bf16 lsB[128 * 64];
    const int tid  = threadIdx.x;
    const int lane = tid & 63;
    const int wave = tid >> 6;
    const int wr = wave >> 1, wc = wave & 1;
    const int m0 = blockIdx.x * 128, n0 = blockIdx.y * 128;
    const int kz = blockIdx.z;
    const int Kc = K / kSplit;
    const int q  = lane & 7;
    const int rb = wave * 32 + (lane >> 3);

    f32x4 acc[4][4] = {};

    for (int k0 = kz * Kc; k0 < kz * Kc + Kc; k0 += 64) {
        #pragma unroll
        for (int i = 0; i < 4; ++i) {
            const int row = rb + i * 8;
            const int sk  = (q * 8) ^ ((row & 7) << 3);
            gload_lds16(A + (size_t)(m0 + row) * lda + k0 + sk,
                        &lsA[(wave * 4 + i) * 512]);
            int rw = n0 + row; rw = rw < N ? rw : N - 1;
            gload_lds16(W + (size_t)rw * ldb + k0 + sk,
                        &lsB[(wave * 4 + i) * 512]);
        }
        __syncthreads();
        #pragma unroll
        for (int kk = 0; kk < 2; ++kk) {
            bf16x8 af[4], bf[4];
            #pragma unroll
            for (int m = 0; m < 4; ++m) {
                const int row = wr * 64 + m * 16 + (lane & 15);
                const int kb  = (kk * 32 + (lane >> 4) * 8) ^ ((row & 7) << 3);
                af[m] = *(const bf16x8*)&lsA[row * 64 + kb];
            }
            #pragma unroll
            for (int n = 0; n < 4; ++n) {
                const int row = wc * 64 + n * 16 + (lane & 15);
                const int kb  = (kk * 32 + (lane >> 4) * 8) ^ ((row & 7) << 3);
                bf[n] = *(const bf16x8*)&lsB[row * 64 + kb];
            }
            #pragma unroll
            for (int m = 0; m < 4; ++m)
            #pragma unroll
            for (int n = 0; n < 4; ++n)
                acc[m][n] = __builtin_amdgcn_mfma_f32_16x16x32_bf16(af[m], bf[n], acc[m][n], 0, 0, 0);
        }
        __syncthreads();
    }

    float* Cout = (EPI == 5) ? C + (size_t)kz * M * ldc : C;
    const int cr = (lane >> 4) * 4, cc = lane & 15;
    #pragma unroll
    for (int mi = 0; mi < 4; ++mi)
    #pragma unroll
    for (int ni = 0; ni < 4; ++ni) {
        const int c = n0 + wc * 64 + ni * 16 + cc;
        if (c >= N) continue;
        #pragma unroll
        for (int g = 0; g < 4; ++g) {
            const int r = m0 + wr * 64 + mi * 16 + cr + g;
            float v = acc[mi][ni][g];
            if (EPI == 1) {
                float xv = v + aux[c];
                Cout[(size_t)r * ldc + c] = (xv > 20.f) ? xv : log1pf(__expf(xv));
            } else if (EPI == 6) {
                const int rr = (c < (N >> 1)) ? r : (M - 1 - r);
                Cb[(size_t)rr * ldc + c] = (__bf16)v;
            } else {
                Cout[(size_t)r * ldc + c] = v;
            }
        }
    }
}

// ---------------------------------------------------------------- fused gate/up MLP GEMM
__global__ __launch_bounds__(256) void gemm_mlp(
    const __bf16* __restrict__ A, const __bf16* __restrict__ Wg,
    const __bf16* __restrict__ Wu, __bf16* __restrict__ m16,
    int M, int N, int K, int lda, int ldb, int ldm)
{
    __shared__ __bf16 lsA[128 * 64];
    __shared__ __bf16 lsB[128 * 64];
    const int tid  = threadIdx.x;
    const int lane = tid & 63;
    const int wave = tid >> 6;
    const int wr = wave >> 1, wc = wave & 1;
    const int m0 = blockIdx.x * 128, n0 = blockIdx.y * 64;
    const int q  = lane & 7;
    const int rb = wave * 32 + (lane >> 3);

    f32x4 acc[4][4] = {};

    for (int k0 = 0; k0 < K; k0 += 64) {
        #pragma unroll
        for (int i = 0; i < 4; ++i) {
            const int row = rb + i * 8;
            const int sk  = (q * 8) ^ ((row & 7) << 3);
            gload_lds16(A + (size_t)(m0 + row) * lda + k0 + sk,
                        &lsA[(wave * 4 + i) * 512]);
            const __bf16* src = (row < 64) ? Wg + (size_t)(n0 + row) * ldb
                                           : Wu + (size_t)(n0 + row - 64) * ldb;
            gload_lds16(src + k0 + sk, &lsB[(wave * 4 + i) * 512]);
        }
        __syncthreads();
        #pragma unroll
        for (int kk = 0; kk < 2; ++kk) {
            bf16x8 af[4], bf[4];
            #pragma unroll
            for (int m = 0; m < 4; ++m) {
                const int row = wr * 64 + m * 16 + (lane & 15);
                const int kb  = (kk * 32 + (lane >> 4) * 8) ^ ((row & 7) << 3);
                af[m] = *(const bf16x8*)&lsA[row * 64 + kb];
            }
            #pragma unroll
            for (int n = 0; n < 4; ++n) {
                const int row = wc * 32 + (n & 1) * 16 + (n >> 1) * 64 + (lane & 15);
                const int kb  = (kk * 32 + (lane >> 4) * 8) ^ ((row & 7) << 3);
                bf[n] = *(const bf16x8*)&lsB[row * 64 + kb];
            }
            #pragma unroll
            for (int m = 0; m < 4; ++m)
            #pragma unroll
            for (int n = 0; n < 4; ++n)
                acc[m][n] = __builtin_amdgcn_mfma_f32_16x16x32_bf16(af[m], bf[n], acc[m][n], 0, 0, 0);
        }
        __syncthreads();
    }

    const int cr = (lane >> 4) * 4, cc = lane & 15;
    #pragma unroll
    for (int mi = 0; mi < 4; ++mi)
    #pragma unroll
    for (int nn = 0; nn < 2; ++nn) {
        const int c = n0 + wc * 32 + nn * 16 + cc;
        #pragma unroll
        for (int g = 0; g < 4; ++g) {
            const int r = m0 + wr * 64 + mi * 16 + cr + g;
            const float gv = acc[mi][nn][g];
            const float uv = acc[mi][nn + 2][g];
            m16[(size_t)r * ldm + c] = (__bf16)(gv / (1.f + __expf(-gv)) * uv);
        }
    }
}

// ---------------------------------------------------------------- batched f32 -> bf16 weight convert
#define NJOBS 9
struct CvtJobs {
    const float* src[NJOBS];
    __bf16* dst[NJOBS];
    int cum[NJOBS + 1];
};
__global__ __launch_bounds__(256) void cvt_multi(CvtJobs j, int total8) {
    const int g = blockIdx.x * 256 + threadIdx.x;
    if (g >= total8) return;
    for (int i = 0; i < NJOBS; ++i) {
        if (g < j.cum[i + 1]) {
            const int off = (g - j.cum[i]) * 8;
            const float4 a = *(const float4*)(j.src[i] + off);
            const float4 b = *(const float4*)(j.src[i] + off + 4);
            bf16x8 o;
            o[0]=(__bf16)a.x; o[1]=(__bf16)a.y; o[2]=(__bf16)a.z; o[3]=(__bf16)a.w;
            o[4]=(__bf16)b.x; o[5]=(__bf16)b.y; o[6]=(__bf16)b.z; o[7]=(__bf16)b.w;
            *(bf16x8*)(j.dst[i] + off) = o;
            return;
        }
    }
}

// out_w_f/out_w_b (1024 x 2048 f32) -> wOUTcat (1024 x 4096 bf16, [f|b])
__global__ __launch_bounds__(256) void cvt_outw(
    const float* __restrict__ wf, const float* __restrict__ wb, __bf16* __restrict__ dst)
{
    const int g = blockIdx.x * 256 + threadIdx.x;
    const int half = g >> 18;
    const int i = (g & 262143) * 8;
    const int r = i >> 11, c = i & 2047;
    const float* src = (half ? wb : wf) + (size_t)r * 2048 + c;
    const float4 a = *(const float4*)src;
    const float4 b = *(const float4*)(src + 4);
    bf16x8 o;
    o[0]=(__bf16)a.x; o[1]=(__bf16)a.y; o[2]=(__bf16)a.z; o[3]=(__bf16)a.w;
    o[4]=(__bf16)b.x; o[5]=(__bf16)b.y; o[6]=(__bf16)b.z; o[7]=(__bf16)b.w;
    *(bf16x8*)(dst + (size_t)r * 4096 + half * 2048 + c) = o;
}

// ---------------------------------------------------------------- rmsnorm1 (+mask) -> bf16 h
__global__ __launch_bounds__(256) void rmsnorm_mask_kernel(
    const float* __restrict__ x, const float* __restrict__ w, const float* __restrict__ mask,
    __bf16* __restrict__ h16)
{
    __shared__ float sred[4];
    const int row = blockIdx.x, t = threadIdx.x;
    float4 v = ((const float4*)(x + (size_t)row * DMODEL))[t];
    float ss = v.x*v.x + v.y*v.y + v.z*v.z + v.w*v.w;
    #pragma unroll
    for (int m = 1; m < 64; m <<= 1) ss += __shfl_xor(ss, m);
    if ((t & 63) == 0) sred[t >> 6] = ss;
    __syncthreads();
    ss = sred[0] + sred[1] + sred[2] + sred[3];
    const float scale = rsqrtf(ss * (1.f / DMODEL) + 1e-6f) * mask[row];
    float4 wv = ((const float4*)w)[t];
    bf16x4 o;
    o[0] = (__bf16)(v.x * wv.x * scale); o[1] = (__bf16)(v.y * wv.y * scale);
    o[2] = (__bf16)(v.z * wv.z * scale); o[3] = (__bf16)(v.w * wv.w * scale);
    *(bf16x4*)&h16[(size_t)row * DMODEL + t * 4] = o;
}

// ---------------------------------------------------------------- causal depthwise conv (k=4) + silu, both dirs
__global__ __launch_bounds__(256) void conv_silu_kernel(
    const __bf16* __restrict__ xz,
    const float* __restrict__ w0, const float* __restrict__ b0,
    const float* __restrict__ w1, const float* __restrict__ b1,
    __bf16* __restrict__ xc16)
{
    const int idx = blockIdx.x * 256 + threadIdx.x;   // over L*DCAT
    const int dcat = idx & (DCAT - 1);
    const int t = idx >> 12;
    const int dir = dcat >> 11, dloc = dcat & 2047;
    const float* w = (dir ? w1 : w0) + dloc * 4;
    float acc = (dir ? b1 : b0)[dloc];
    const float4 wv = *(const float4*)w;
    const float wj[4] = {wv.x, wv.y, wv.z, wv.w};
    const __bf16* src = xz + dir * 4096 + dloc;
    #pragma unroll
    for (int jj = 0; jj < 4; ++jj) {
        const int tt = t - 3 + jj;
        if (tt >= 0) acc += wj[jj] * (float)src[(size_t)tt * XZLD];
    }
    xc16[(size_t)idx] = (__bf16)(acc / (1.f + __expf(-acc)));
}

// ---------------------------------------------------------------- dbc finalize: sum 8 xproj K-partials, both dirs
__global__ __launch_bounds__(256) void dbc_finalize(
    const float* __restrict__ P, float* __restrict__ dbc, __bf16* __restrict__ dbc16)
{
    const int i = blockIdx.x * 256 + threadIdx.x;     // over 2*L*96
    const int dir = i / LS96, rem = i - dir * LS96;
    float v = 0.f;
    #pragma unroll
    for (int s = 0; s < 8; ++s) v += P[(size_t)dir * 8 * LS96 + (size_t)s * LS96 + rem];
    dbc[i] = v;
    const int r = rem / 96, c = rem - r * 96;
    if (c < DTRANK) dbc16[(size_t)dir * L_SEQ * DTRANK + r * DTRANK + c] = (__bf16)v;
}

// ---------------------------------------------------------------- scan phase 1 (reg-state, both dirs)
__global__ __launch_bounds__(256) void scan_p1(
    const __bf16* __restrict__ u, const float* __restrict__ dt,
    const float* __restrict__ dbc, const float* __restrict__ A0, const float* __restrict__ A1,
    __bf16* __restrict__ Pb, __bf16* __restrict__ Sb)
{
    __shared__ float sB[TC * 16];
    const int tid = threadIdx.x;
    const int c = blockIdx.x;
    const int dcat = blockIdx.y * 256 + tid;
    const int dir = blockIdx.y >> 3;
    const int dloc = dcat & 2047;
    const int t0 = c * TC;
    const float* dbcD = dbc + (size_t)dir * LS96;
    for (int i = tid; i < TC * 16; i += 256)
        sB[i] = dbcD[(t0 + (i >> 4)) * DBC_LD + DTRANK + (i & 15)];
    __syncthreads();
    const float* Alog = (dir ? A1 : A0) + (size_t)dloc * 16;
    float A[16], h[16], Pa[16];
    #pragma unroll
    for (int n = 0; n < 16; n += 4) {
        const float4 av = *(const float4*)(Alog + n);
        A[n]   = -__expf(av.x); A[n+1] = -__expf(av.y);
        A[n+2] = -__expf(av.z); A[n+3] = -__expf(av.w);
    }
    #pragma unroll
    for (int n = 0; n < 16; ++n) { h[n] = 0.f; Pa[n] = 1.f; }
    #pragma unroll 2
    for (int t = 0; t < TC; ++t) {
        const float dtv = dt[(size_t)(t0 + t) * DCAT + dcat];
        const float du  = dtv * (float)u[(size_t)(t0 + t) * DCAT + dcat];
        #pragma unroll
        for (int n = 0; n < 16; ++n) {
            const float a = __expf(dtv * A[n]);
            h[n] = a * h[n] + du * sB[t * 16 + n];
            Pa[n] *= a;
        }
    }
    __bf16* pp = Pb + ((size_t)c * DCAT + dcat) * 16;
    __bf16* sp = Sb + ((size_t)c * DCAT + dcat) * 16;
    bf16x8 pv0, pv1, sv0, sv1;
    #pragma unroll
    for (int n = 0; n < 8; ++n) {
        pv0[n] = (__bf16)Pa[n]; pv1[n] = (__bf16)Pa[n + 8];
        sv0[n] = (__bf16)h[n];  sv1[n] = (__bf16)h[n + 8];
    }
    *(bf16x8*)pp = pv0; *(bf16x8*)(pp + 8) = pv1;
    *(bf16x8*)sp = sv0; *(bf16x8*)(sp + 8) = sv1;
}

// ---------------------------------------------------------------- scan phase 2: combine chunk states
__global__ __launch_bounds__(256) void scan_mid(
    const __bf16* __restrict__ Pb, const __bf16* __restrict__ Sb, __bf16* __restrict__ Hb)
{
    const int i = blockIdx.x * 256 + threadIdx.x;    // (dcat,n) flat, 0..65535
    float H = 0.f;
    for (int c = 0; c < NC; ++c) {
        Hb[(size_t)c * 65536 + i] = (__bf16)H;
        H = (float)Pb[(size_t)c * 65536 + i] * H + (float)Sb[(size_t)c * 65536 + i];
    }
}

// ---------------------------------------------------------------- scan phase 3: recompute + y + gate -> ygcat
__global__ __launch_bounds__(256) void scan_p3(
    const __bf16* __restrict__ u, const float* __restrict__ dt,
    const float* __restrict__ dbc, const float* __restrict__ A0, const float* __restrict__ A1,
    const float* __restrict__ Dp0, const float* __restrict__ Dp1,
    const __bf16* __restrict__ Hb, const __bf16* __restrict__ xz,
    __bf16* __restrict__ ygcat)
{
    __shared__ float sB[TC * 16], sC[TC * 16];
    const int tid = threadIdx.x;
    const int c = blockIdx.x;
    const int dcat = blockIdx.y * 256 + tid;
    const int dir = blockIdx.y >> 3;
    const int dloc = dcat & 2047;
    const int t0 = c * TC;
    const float* dbcD = dbc + (size_t)dir * LS96;
    for (int i = tid; i < TC * 16; i += 256) {
        sB[i] = dbcD[(t0 + (i >> 4)) * DBC_LD + DTRANK + (i & 15)];
        sC[i] = dbcD[(t0 + (i >> 4)) * DBC_LD + DTRANK + DSTATE + (i & 15)];
    }
    __syncthreads();
    const float* Alog = (dir ? A1 : A0) + (size_t)dloc * 16;
    const __bf16* hp = Hb + ((size_t)c * DCAT + dcat) * 16;
    const bf16x8 hv0 = *(const bf16x8*)hp;
    const bf16x8 hv1 = *(const bf16x8*)(hp + 8);
    float A[16], h[16];
    #pragma unroll
    for (int n = 0; n < 8; ++n) { h[n] = (float)hv0[n]; h[n + 8] = (float)hv1[n]; }
    #pragma unroll
    for (int n = 0; n < 16; n += 4) {
        const float4 av = *(const float4*)(Alog + n);
        A[n]   = -__expf(av.x); A[n+1] = -__expf(av.y);
        A[n+2] = -__expf(av.z); A[n+3] = -__expf(av.w);
    }
    const float Dv = (dir ? Dp1 : Dp0)[dloc];
    const __bf16* zsrc = xz + dir * 4096 + 2048 + dloc;
    #pragma unroll 2
    for (int t = 0; t < TC; ++t) {
        const float dtv = dt[(size_t)(t0 + t) * DCAT + dcat];
        const float uv  = (float)u[(size_t)(t0 + t) * DCAT + dcat];
        const float du  = dtv * uv;
        float y = uv * Dv;
        #pragma unroll
        for (int n = 0; n < 16; ++n) {
            const float a = __expf(dtv * A[n]);
            h[n] = a * h[n] + du * sB[t * 16 + n];
            y += h[n] * sC[t * 16 + n];
        }
        const float zv = (float)zsrc[(size_t)(t0 + t) * XZLD];
        const int orow = dir ? (L_SEQ - 1 - (t0 + t)) : (t0 + t);
        ygcat[(size_t)orow * DCAT + dcat] = (__bf16)(y * (zv / (1.f + __expf(-zv))));
    }
}

// ---------------------------------------------------------------- x2 = x + rmsnorm(sum P0..3)*mw ; h2_16
__global__ __launch_bounds__(256) void addnorm2_kernel(
    const float* __restrict__ x0, const float* __restrict__ P,
    const float* __restrict__ mw, const float* __restrict__ w2,
    float* __restrict__ x2, __bf16* __restrict__ h2_16)
{
    __shared__ float sred[8];
    const int row = blockIdx.x, t = threadIdx.x;
    const size_t PS = (size_t)L_SEQ * DMODEL;
    float4 yv = ((const float4*)(P + (size_t)row * DMODEL))[t];
    #pragma unroll
    for (int s = 1; s < 4; ++s) {
        float4 pv = ((const float4*)(P + s * PS + (size_t)row * DMODEL))[t];
        yv.x += pv.x; yv.y += pv.y; yv.z += pv.z; yv.w += pv.w;
    }
    float ss = yv.x*yv.x + yv.y*yv.y + yv.z*yv.z + yv.w*yv.w;
    #pragma unroll
    for (int m = 1; m < 64; m <<= 1) ss += __shfl_xor(ss, m);
    if ((t & 63) == 0) sred[t >> 6] = ss;
    __syncthreads();
    const float s1 = sred[0] + sred[1] + sred[2] + sred[3];
    const float sc1 = rsqrtf(s1 * (1.f / DMODEL) + 1e-6f);
    float4 xv = ((const float4*)(x0 + (size_t)row * DMODEL))[t];
    float4 mv = ((const float4*)mw)[t];
    float4 o;
    o.x = xv.x + mv.x * yv.x * sc1; o.y = xv.y + mv.y * yv.y * sc1;
    o.z = xv.z + mv.z * yv.z * sc1; o.w = xv.w + mv.w * yv.w * sc1;
    ((float4*)(x2 + (size_t)row * DMODEL))[t] = o;
    float s2 = o.x*o.x + o.y*o.y + o.z*o.z + o.w*o.w;
    #pragma unroll
    for (int m = 1; m < 64; m <<= 1) s2 += __shfl_xor(s2, m);
    if ((t & 63) == 0) sred[4 + (t >> 6)] = s2;
    __syncthreads();
    const float st = sred[4] + sred[5] + sred[6] + sred[7];
    const float sc2 = rsqrtf(st * (1.f / DMODEL) + 1e-6f);
    float4 wv = ((const float4*)w2)[t];
    bf16x4 o2;
    o2[0] = (__bf16)(wv.x * o.x * sc2); o2[1] = (__bf16)(wv.y * o.y * sc2);
    o2[2] = (__bf16)(wv.z * o.z * sc2); o2[3] = (__bf16)(wv.w * o.w * sc2);
    *(bf16x4*)&h2_16[(size_t)row * DMODEL + t * 4] = o2;
}

// ---------------------------------------------------------------- d_out = x2 + sum P0..3
__global__ __launch_bounds__(256) void addout_kernel(
    const float* __restrict__ x2, const float* __restrict__ P, float* __restrict__ out)
{
    const size_t i = ((size_t)blockIdx.x * 256 + threadIdx.x) * 4;
    const size_t PS = (size_t)L_SEQ * DMODEL;
    float4 v = *(const float4*)(x2 + i);
    #pragma unroll
    for (int s = 0; s < 4; ++s) {
        const float4 pv = *(const float4*)(P + s * PS + i);
        v.x += pv.x; v.y += pv.y; v.z += pv.z; v.w += pv.w;
    }
    *(float4*)(out + i) = v;
}

// ---------------------------------------------------------------- launch
extern "C" void kernel_launch(void* const* d_in, const int* in_sizes, int n_in,
                              void* d_out, int out_size, void* d_ws, size_t ws_size,
                              hipStream_t stream)
{
    const float* x       = (const float*)d_in[0];
    const float* mask    = (const float*)d_in[1];
    const float* mnorm_w = (const float*)d_in[2];
    const float* ln1_w   = (const float*)d_in[3];
    const float* ln2_w   = (const float*)d_in[4];
    const float* gate_w  = (const float*)d_in[5];
    const float* up_w    = (const float*)d_in[6];
    const float* down_w  = (const float*)d_in[7];
    const float* in_w[2]    = {(const float*)d_in[8],  (const float*)d_in[17]};
    const float* conv_w[2]  = {(const float*)d_in[9],  (const float*)d_in[18]};
    const float* conv_b[2]  = {(const float*)d_in[10], (const float*)d_in[19]};
    const float* xproj_w[2] = {(const float*)d_in[11], (const float*)d_in[20]};
    const float* dt_w[2]    = {(const float*)d_in[12], (const float*)d_in[21]};
    const float* dt_b[2]    = {(const float*)d_in[13], (const float*)d_in[22]};
    const float* A_log[2]   = {(const float*)d_in[14], (const float*)d_in[23]};
    const float* Dp[2]      = {(const float*)d_in[15], (const float*)d_in[24]};
    const float* out_w[2]   = {(const float*)d_in[16], (const float*)d_in[25]};

    float* ws = (float*)d_ws;
    const size_t MF = 1u << 20;   // 1M floats = 4MB
    __bf16* h16    = (__bf16*)(ws);                  // [0,1)MF
    float*  x2     = ws + 1 * MF;                    // [1,3)
    __bf16* xzcat  = (__bf16*)(ws + 3 * MF);         // [3,11)   L x 8192 bf16
    __bf16* xc16   = (__bf16*)(ws + 11 * MF);        // [11,15)  L x 4096 bf16
    float*  dtb    = ws + 15 * MF;                   // [15,23)  L x 4096 f32 (gemmP alias)
    float*  dbc    = ws + 23 * MF;                   // [23,23.5) 2 x L x 96 f32
    __bf16* dbc16  = (__bf16*)(ws + 23 * MF + 524288);  // 2 x L x 64 bf16
    __bf16* Pb     = (__bf16*)(ws + 24 * MF);        // [24,26) bf16 (dbcP alias [24,27))
    __bf16* Sb     = (__bf16*)(ws + 26 * MF);        // [26,28)
    float*  dbcP   = ws + 24 * MF;                   // 16 x L x 96 f32 = 3MF
    __bf16* Hb     = (__bf16*)(ws + 28 * MF);        // [28,30)
    __bf16* ygcat  = (__bf16*)(ws + 30 * MF);        // [30,34)  L x 4096 bf16 (mbuf16 alias)
    __bf16* h2_16  = (__bf16*)(ws + 34 * MF);        // [34,35)
    __bf16* wbase  = (__bf16*)(ws + 35 * MF);
    const size_t M4 = 4u << 20, M2 = 2u << 20;
    __bf16* wINcat  = wbase;                         // 8192 x 1024
    __bf16* wOUTcat = wbase + 2 * M4;                // 1024 x 4096
    __bf16* wG      = wbase + 3 * M4;
    __bf16* wU      = wbase + 4 * M4;
    __bf16* wDN     = wbase + 5 * M4;
    __bf16* wXP[2]  = {wbase + 6 * M4,            wbase + 6 * M4 + 196608};
    __bf16* wDT[2]  = {wbase + 6 * M4 + 393216,   wbase + 6 * M4 + 524288};
    __bf16* mbuf16  = ygcat;
    float*  gemmP   = dtb;

    // ---- weight conversion
    CvtJobs j;
    const float* srcs[NJOBS] = {in_w[0], in_w[1], gate_w, up_w, down_w,
                                xproj_w[0], xproj_w[1], dt_w[0], dt_w[1]};
    __bf16* dsts[NJOBS] = {wINcat, wINcat + M4, wG, wU, wDN, wXP[0], wXP[1], wDT[0], wDT[1]};
    const int szs[NJOBS] = {4194304, 4194304, 4194304, 4194304, 4194304,
                            196608, 196608, 131072, 131072};
    int cum = 0;
    for (int i = 0; i < NJOBS; ++i) {
        j.src[i] = srcs[i]; j.dst[i] = dsts[i]; j.cum[i] = cum; cum += szs[i] / 8;
    }
    j.cum[NJOBS] = cum;
    cvt_multi<<<(cum + 255) / 256, 256, 0, stream>>>(j, cum);
    cvt_outw<<<(2 * 1024 * 2048 / 8) / 256, 256, 0, stream>>>(out_w[0], out_w[1], wOUTcat);

    rmsnorm_mask_kernel<<<L_SEQ, 256, 0, stream>>>(x, ln1_w, mask, h16);

    // fused bidirectional in-proj: xzcat = h @ [in_w_f; in_w_b]^T, b-half rows flipped, bf16 out
    gemm16<6><<<dim3(16, 64), 256, 0, stream>>>(
        h16, wINcat, nullptr, nullptr, xzcat, 2048, 8192, 1024, 1024, 1024, 8192, 1);

    // conv + silu over both dirs -> xc16 (L x 4096)
    conv_silu_kernel<<<(L_SEQ * DCAT) / 256, 256, 0, stream>>>(
        xzcat, conv_w[0], conv_b[0], conv_w[1], conv_b[1], xc16);

    // xproj partials (per dir, K=2048 split 8)
    for (int dir = 0; dir < 2; ++dir)
        gemm16<5><<<dim3(16, 1, 8), 256, 0, stream>>>(
            xc16 + dir * 2048, wXP[dir], dbcP + (size_t)dir * 8 * LS96, nullptr, nullptr,
            2048, 96, 2048, 4096, 2048, 96, 8);
    dbc_finalize<<<(2 * LS96) / 256, 256, 0, stream>>>(dbcP, dbc, dbc16);

    // dt = softplus(dt_raw @ dt_w^T + dt_b) per dir -> dtb cols [dir*2048, ...)
    for (int dir = 0; dir < 2; ++dir)
        gemm16<1><<<dim3(16, 16), 256, 0, stream>>>(
            dbc16 + (size_t)dir * L_SEQ * DTRANK, wDT[dir], dtb + dir * 2048, dt_b[dir],
            nullptr, 2048, 2048, 64, 64, 64, 4096, 1);

    // chunk-parallel selective scan over both dirs -> ygcat
    scan_p1<<<dim3(NC, 16), 256, 0, stream>>>(
        xc16, dtb, dbc, A_log[0], A_log[1], Pb, Sb);
    scan_mid<<<65536 / 256, 256, 0, stream>>>(Pb, Sb, Hb);
    scan_p3<<<dim3(NC, 16), 256, 0, stream>>>(
        xc16, dtb, dbc, A_log[0], A_log[1], Dp[0], Dp[1], Hb, xzcat, ygcat);

    // fused out-proj: partials = ygcat @ wOUTcat^T  (2048 x 1024, K=4096, split 4)
    gemm16<5><<<dim3(16, 8, 4), 256, 0, stream>>>(
        ygcat, wOUTcat, gemmP, nullptr, nullptr, 2048, 1024, 4096, 4096, 4096, 1024, 4);
    addnorm2_kernel<<<L_SEQ, 256, 0, stream>>>(x, gemmP, mnorm_w, ln2_w, x2, h2_16);

    // MLP
    gemm_mlp<<<dim3(16, 64), 256, 0, stream>>>(
        h2_16, wG, wU, mbuf16, 2048, 4096, 1024, 1024, 1024, 4096);
    gemm16<5><<<dim3(16, 8, 4), 256, 0, stream>>>(
        mbuf16, wDN, gemmP, nullptr, nullptr, 2048, 1024, 4096, 4096, 4096, 1024, 4);
    addout_kernel<<<(L_SEQ * DMODEL) / (256 * 4), 256, 0, stream>>>(
        x2, gemmP, (float*)d_out);
}

// Round 7
// 359.293 us; speedup vs baseline: 10.8969x; 1.0688x over previous
//
#include <hip/hip_runtime.h>

#define L_SEQ 2048
#define DMODEL 1024
#define DINNER 2048
#define DSTATE 16
#define DTRANK 64
#define DBC_LD 96
#define NC 64   // scan chunks
#define TC 32   // timesteps per chunk
#define DCAT 4096          // both dirs' channels
#define XZLD 8192          // xzcat row stride
#define LS96 (L_SEQ * 96)

typedef __bf16 bf16x8 __attribute__((ext_vector_type(8)));
typedef __bf16 bf16x4 __attribute__((ext_vector_type(4)));
typedef float f32x4 __attribute__((ext_vector_type(4)));

__device__ __forceinline__ void gload_lds16(const void* g, void* l) {
    __builtin_amdgcn_global_load_lds(
        (const __attribute__((address_space(1))) void*)g,
        (__attribute__((address_space(3))) void*)l, 16, 0, 0);
}

// XCD-bijective swizzle for 2D grids with gridDim.x == 16, nwg % 8 == 0:
// each XCD gets a contiguous n-panel (m-fast within it) for L2 locality.
__device__ __forceinline__ void xcd_swz16(int& bx, int& by, int nwg) {
    const int lin = by * 16 + bx;
    const int s = (lin & 7) * (nwg >> 3) + (lin >> 3);
    bx = s & 15;
    by = s >> 4;
}

// ---------------------------------------------------------------- shared GEMM core
// acc += A[m0+.., k0b..k0e) x W[n0+.., ..]^T ; 128x128 tile, 4 waves, BK=64,
// global_load_lds + XOR-swizzled LDS. N-clamp on W rows for N<128 tiles.
__device__ __forceinline__ void gemm_core(
    const __bf16* __restrict__ A, const __bf16* __restrict__ W,
    __bf16* lsA, __bf16* lsB,
    int m0, int n0, int N, int lda, int ldb, int k0b, int k0e,
    f32x4 (&acc)[4][4])
{
    const int tid  = threadIdx.x;
    const int lane = tid & 63;
    const int wave = tid >> 6;
    const int wr = wave >> 1, wc = wave & 1;
    const int q  = lane & 7;
    const int rb = wave * 32 + (lane >> 3);

    for (int k0 = k0b; k0 < k0e; k0 += 64) {
        #pragma unroll
        for (int i = 0; i < 4; ++i) {
            const int row = rb + i * 8;
            const int sk  = (q * 8) ^ ((row & 7) << 3);
            gload_lds16(A + (size_t)(m0 + row) * lda + k0 + sk,
                        &lsA[(wave * 4 + i) * 512]);
            int rw = n0 + row; rw = rw < N ? rw : N - 1;
            gload_lds16(W + (size_t)rw * ldb + k0 + sk,
                        &lsB[(wave * 4 + i) * 512]);
        }
        __syncthreads();
        #pragma unroll
        for (int kk = 0; kk < 2; ++kk) {
            bf16x8 af[4], bfr[4];
            #pragma unroll
            for (int m = 0; m < 4; ++m) {
                const int row = wr * 64 + m * 16 + (lane & 15);
                const int kb  = (kk * 32 + (lane >> 4) * 8) ^ ((row & 7) << 3);
                af[m] = *(const bf16x8*)&lsA[row * 64 + kb];
            }
            #pragma unroll
            for (int n = 0; n < 4; ++n) {
                const int row = wc * 64 + n * 16 + (lane & 15);
                const int kb  = (kk * 32 + (lane >> 4) * 8) ^ ((row & 7) << 3);
                bfr[n] = *(const bf16x8*)&lsB[row * 64 + kb];
            }
            #pragma unroll
            for (int m = 0; m < 4; ++m)
            #pragma unroll
            for (int n = 0; n < 4; ++n)
                acc[m][n] = __builtin_amdgcn_mfma_f32_16x16x32_bf16(af[m], bfr[n], acc[m][n], 0, 0, 0);
        }
        __syncthreads();
    }
}

#define EPI_SETUP \
    const int lane = threadIdx.x & 63; \
    const int wave = threadIdx.x >> 6; \
    const int wr = wave >> 1, wc = wave & 1; \
    const int cr = (lane >> 4) * 4, cc = lane & 15;

// ---------------------------------------------------------------- in-proj: bf16 store, row-flip cols >= N/2
__global__ __launch_bounds__(256) void k_inproj(
    const __bf16* __restrict__ A, const __bf16* __restrict__ W, __bf16* __restrict__ Cb,
    int M, int N, int K, int lda, int ldb, int ldc)
{
    __shared__ __bf16 lsA[128 * 64], lsB[128 * 64];
    int bx = blockIdx.x, by = blockIdx.y;
    xcd_swz16(bx, by, 1024);
    const int m0 = bx * 128, n0 = by * 128;
    f32x4 acc[4][4] = {};
    gemm_core(A, W, lsA, lsB, m0, n0, N, lda, ldb, 0, K, acc);
    EPI_SETUP
    #pragma unroll
    for (int mi = 0; mi < 4; ++mi)
    #pragma unroll
    for (int ni = 0; ni < 4; ++ni) {
        const int c = n0 + wc * 64 + ni * 16 + cc;
        #pragma unroll
        for (int g = 0; g < 4; ++g) {
            const int r = m0 + wr * 64 + mi * 16 + cr + g;
            const int rr = (c < (N >> 1)) ? r : (M - 1 - r);
            Cb[(size_t)rr * ldc + c] = (__bf16)acc[mi][ni][g];
        }
    }
}

// ---------------------------------------------------------------- xproj: both dirs + K-split in z
// z = dir*8 + kz; partial f32 to P + (dir*8+kz)*LS96
__global__ __launch_bounds__(256) void k_xproj(
    const __bf16* __restrict__ A, const __bf16* __restrict__ W0, const __bf16* __restrict__ W1,
    float* __restrict__ P)
{
    __shared__ __bf16 lsA[128 * 64], lsB[128 * 64];
    const int dir = blockIdx.z >> 3, kz = blockIdx.z & 7;
    const int m0 = blockIdx.x * 128, n0 = 0;
    const __bf16* W = dir ? W1 : W0;
    f32x4 acc[4][4] = {};
    gemm_core(A + dir * 2048, W, lsA, lsB, m0, n0, 96, 4096, 2048,
              kz * 256, kz * 256 + 256, acc);
    float* Cout = P + (size_t)blockIdx.z * LS96;
    EPI_SETUP
    #pragma unroll
    for (int mi = 0; mi < 4; ++mi)
    #pragma unroll
    for (int ni = 0; ni < 4; ++ni) {
        const int c = wc * 64 + ni * 16 + cc;
        if (c >= 96) continue;
        #pragma unroll
        for (int g = 0; g < 4; ++g) {
            const int r = m0 + wr * 64 + mi * 16 + cr + g;
            Cout[(size_t)r * 96 + c] = acc[mi][ni][g];
        }
    }
}

// ---------------------------------------------------------------- dt: both dirs in z; softplus -> bf16 dtb16
__global__ __launch_bounds__(256) void k_dt(
    const __bf16* __restrict__ A, const __bf16* __restrict__ W0, const __bf16* __restrict__ W1,
    const float* __restrict__ aux0, const float* __restrict__ aux1,
    __bf16* __restrict__ Cb)
{
    __shared__ __bf16 lsA[128 * 64], lsB[128 * 64];
    const int dir = blockIdx.z;
    const int m0 = blockIdx.x * 128, n0 = blockIdx.y * 128;
    const __bf16* W = dir ? W1 : W0;
    const float* aux = dir ? aux1 : aux0;
    f32x4 acc[4][4] = {};
    gemm_core(A + (size_t)dir * L_SEQ * DTRANK, W, lsA, lsB, m0, n0, 2048, 64, 64, 0, 64, acc);
    EPI_SETUP
    #pragma unroll
    for (int mi = 0; mi < 4; ++mi)
    #pragma unroll
    for (int ni = 0; ni < 4; ++ni) {
        const int c = n0 + wc * 64 + ni * 16 + cc;
        #pragma unroll
        for (int g = 0; g < 4; ++g) {
            const int r = m0 + wr * 64 + mi * 16 + cr + g;
            const float xv = acc[mi][ni][g] + aux[c];
            const float sp = (xv > 20.f) ? xv : log1pf(__expf(xv));
            Cb[(size_t)r * DCAT + dir * 2048 + c] = (__bf16)sp;
        }
    }
}

// ---------------------------------------------------------------- split-K partial GEMM (out-proj / down-proj)
__global__ __launch_bounds__(256) void k_partial(
    const __bf16* __restrict__ A, const __bf16* __restrict__ W, float* __restrict__ P,
    int M, int N, int K, int lda, int ldb, int ldc, int kSplit)
{
    __shared__ __bf16 lsA[128 * 64], lsB[128 * 64];
    int bx = blockIdx.x, by = blockIdx.y;
    xcd_swz16(bx, by, gridDim.x * gridDim.y);
    const int m0 = bx * 128, n0 = by * 128;
    const int Kc = K / kSplit, kz = blockIdx.z;
    f32x4 acc[4][4] = {};
    gemm_core(A, W, lsA, lsB, m0, n0, N, lda, ldb, kz * Kc, kz * Kc + Kc, acc);
    float* Cout = P + (size_t)kz * M * ldc;
    EPI_SETUP
    #pragma unroll
    for (int mi = 0; mi < 4; ++mi)
    #pragma unroll
    for (int ni = 0; ni < 4; ++ni) {
        const int c = n0 + wc * 64 + ni * 16 + cc;
        #pragma unroll
        for (int g = 0; g < 4; ++g) {
            const int r = m0 + wr * 64 + mi * 16 + cr + g;
            Cout[(size_t)r * ldc + c] = acc[mi][ni][g];
        }
    }
}

// ---------------------------------------------------------------- fused gate/up MLP GEMM
__global__ __launch_bounds__(256) void gemm_mlp(
    const __bf16* __restrict__ A, const __bf16* __restrict__ Wg,
    const __bf16* __restrict__ Wu, __bf16* __restrict__ m16,
    int M, int N, int K, int lda, int ldb, int ldm)
{
    __shared__ __bf16 lsA[128 * 64];
    __shared__ __bf16 lsB[128 * 64];
    const int tid  = threadIdx.x;
    const int lane = tid & 63;
    const int wave = tid >> 6;
    const int wr = wave >> 1, wc = wave & 1;
    int bx = blockIdx.x, by = blockIdx.y;
    xcd_swz16(bx, by, 1024);
    const int m0 = bx * 128, n0 = by * 64;
    const int q  = lane & 7;
    const int rb = wave * 32 + (lane >> 3);

    f32x4 acc[4][4] = {};

    for (int k0 = 0; k0 < K; k0 += 64) {
        #pragma unroll
        for (int i = 0; i < 4; ++i) {
            const int row = rb + i * 8;
            const int sk  = (q * 8) ^ ((row & 7) << 3);
            gload_lds16(A + (size_t)(m0 + row) * lda + k0 + sk,
                        &lsA[(wave * 4 + i) * 512]);
            const __bf16* src = (row < 64) ? Wg + (size_t)(n0 + row) * ldb
                                           : Wu + (size_t)(n0 + row - 64) * ldb;
            gload_lds16(src + k0 + sk, &lsB[(wave * 4 + i) * 512]);
        }
        __syncthreads();
        #pragma unroll
        for (int kk = 0; kk < 2; ++kk) {
            bf16x8 af[4], bfr[4];
            #pragma unroll
            for (int m = 0; m < 4; ++m) {
                const int row = wr * 64 + m * 16 + (lane & 15);
                const int kb  = (kk * 32 + (lane >> 4) * 8) ^ ((row & 7) << 3);
                af[m] = *(const bf16x8*)&lsA[row * 64 + kb];
            }
            #pragma unroll
            for (int n = 0; n < 4; ++n) {
                const int row = wc * 32 + (n & 1) * 16 + (n >> 1) * 64 + (lane & 15);
                const int kb  = (kk * 32 + (lane >> 4) * 8) ^ ((row & 7) << 3);
                bfr[n] = *(const bf16x8*)&lsB[row * 64 + kb];
            }
            #pragma unroll
            for (int m = 0; m < 4; ++m)
            #pragma unroll
            for (int n = 0; n < 4; ++n)
                acc[m][n] = __builtin_amdgcn_mfma_f32_16x16x32_bf16(af[m], bfr[n], acc[m][n], 0, 0, 0);
        }
        __syncthreads();
    }

    const int cr = (lane >> 4) * 4, cc = lane & 15;
    #pragma unroll
    for (int mi = 0; mi < 4; ++mi)
    #pragma unroll
    for (int nn = 0; nn < 2; ++nn) {
        const int c = n0 + wc * 32 + nn * 16 + cc;
        #pragma unroll
        for (int g = 0; g < 4; ++g) {
            const int r = m0 + wr * 64 + mi * 16 + cr + g;
            const float gv = acc[mi][nn][g];
            const float uv = acc[mi][nn + 2][g];
            m16[(size_t)r * ldm + c] = (__bf16)(gv / (1.f + __expf(-gv)) * uv);
        }
    }
}

// ---------------------------------------------------------------- batched f32 -> bf16 weight convert
#define NJOBS 9
struct CvtJobs {
    const float* src[NJOBS];
    __bf16* dst[NJOBS];
    int cum[NJOBS + 1];
};
__global__ __launch_bounds__(256) void cvt_multi(CvtJobs j, int total8) {
    const int g = blockIdx.x * 256 + threadIdx.x;
    if (g >= total8) return;
    for (int i = 0; i < NJOBS; ++i) {
        if (g < j.cum[i + 1]) {
            const int off = (g - j.cum[i]) * 8;
            const float4 a = *(const float4*)(j.src[i] + off);
            const float4 b = *(const float4*)(j.src[i] + off + 4);
            bf16x8 o;
            o[0]=(__bf16)a.x; o[1]=(__bf16)a.y; o[2]=(__bf16)a.z; o[3]=(__bf16)a.w;
            o[4]=(__bf16)b.x; o[5]=(__bf16)b.y; o[6]=(__bf16)b.z; o[7]=(__bf16)b.w;
            *(bf16x8*)(j.dst[i] + off) = o;
            return;
        }
    }
}

// out_w_f/out_w_b (1024 x 2048 f32) -> wOUTcat (1024 x 4096 bf16, [f|b])
__global__ __launch_bounds__(256) void cvt_outw(
    const float* __restrict__ wf, const float* __restrict__ wb, __bf16* __restrict__ dst)
{
    const int g = blockIdx.x * 256 + threadIdx.x;
    const int half = g >> 18;
    const int i = (g & 262143) * 8;
    const int r = i >> 11, c = i & 2047;
    const float* src = (half ? wb : wf) + (size_t)r * 2048 + c;
    const float4 a = *(const float4*)src;
    const float4 b = *(const float4*)(src + 4);
    bf16x8 o;
    o[0]=(__bf16)a.x; o[1]=(__bf16)a.y; o[2]=(__bf16)a.z; o[3]=(__bf16)a.w;
    o[4]=(__bf16)b.x; o[5]=(__bf16)b.y; o[6]=(__bf16)b.z; o[7]=(__bf16)b.w;
    *(bf16x8*)(dst + (size_t)r * 4096 + half * 2048 + c) = o;
}

// ---------------------------------------------------------------- rmsnorm1 (+mask) -> bf16 h
__global__ __launch_bounds__(256) void rmsnorm_mask_kernel(
    const float* __restrict__ x, const float* __restrict__ w, const float* __restrict__ mask,
    __bf16* __restrict__ h16)
{
    __shared__ float sred[4];
    const int row = blockIdx.x, t = threadIdx.x;
    float4 v = ((const float4*)(x + (size_t)row * DMODEL))[t];
    float ss = v.x*v.x + v.y*v.y + v.z*v.z + v.w*v.w;
    #pragma unroll
    for (int m = 1; m < 64; m <<= 1) ss += __shfl_xor(ss, m);
    if ((t & 63) == 0) sred[t >> 6] = ss;
    __syncthreads();
    ss = sred[0] + sred[1] + sred[2] + sred[3];
    const float scale = rsqrtf(ss * (1.f / DMODEL) + 1e-6f) * mask[row];
    float4 wv = ((const float4*)w)[t];
    bf16x4 o;
    o[0] = (__bf16)(v.x * wv.x * scale); o[1] = (__bf16)(v.y * wv.y * scale);
    o[2] = (__bf16)(v.z * wv.z * scale); o[3] = (__bf16)(v.w * wv.w * scale);
    *(bf16x4*)&h16[(size_t)row * DMODEL + t * 4] = o;
}

// ---------------------------------------------------------------- causal depthwise conv (k=4) + silu, both dirs
__global__ __launch_bounds__(256) void conv_silu_kernel(
    const __bf16* __restrict__ xz,
    const float* __restrict__ w0, const float* __restrict__ b0,
    const float* __restrict__ w1, const float* __restrict__ b1,
    __bf16* __restrict__ xc16)
{
    const int idx = blockIdx.x * 256 + threadIdx.x;   // over L*DCAT
    const int dcat = idx & (DCAT - 1);
    const int t = idx >> 12;
    const int dir = dcat >> 11, dloc = dcat & 2047;
    const float* w = (dir ? w1 : w0) + dloc * 4;
    float acc = (dir ? b1 : b0)[dloc];
    const float4 wv = *(const float4*)w;
    const float wj[4] = {wv.x, wv.y, wv.z, wv.w};
    const __bf16* src = xz + dir * 4096 + dloc;
    #pragma unroll
    for (int jj = 0; jj < 4; ++jj) {
        const int tt = t - 3 + jj;
        if (tt >= 0) acc += wj[jj] * (float)src[(size_t)tt * XZLD];
    }
    xc16[(size_t)idx] = (__bf16)(acc / (1.f + __expf(-acc)));
}

// ---------------------------------------------------------------- dbc finalize: sum 8 xproj K-partials, both dirs
__global__ __launch_bounds__(256) void dbc_finalize(
    const float* __restrict__ P, float* __restrict__ dbc, __bf16* __restrict__ dbc16)
{
    const int i = blockIdx.x * 256 + threadIdx.x;     // over 2*L*96
    const int dir = i / LS96, rem = i - dir * LS96;
    float v = 0.f;
    #pragma unroll
    for (int s = 0; s < 8; ++s) v += P[(size_t)dir * 8 * LS96 + (size_t)s * LS96 + rem];
    dbc[i] = v;
    const int r = rem / 96, c = rem - r * 96;
    if (c < DTRANK) dbc16[(size_t)dir * L_SEQ * DTRANK + r * DTRANK + c] = (__bf16)v;
}

// ---------------------------------------------------------------- scan phase 1 (reg-state, both dirs)
__global__ __launch_bounds__(256) void scan_p1(
    const __bf16* __restrict__ u, const __bf16* __restrict__ dt,
    const float* __restrict__ dbc, const float* __restrict__ A0, const float* __restrict__ A1,
    __bf16* __restrict__ Pb, __bf16* __restrict__ Sb)
{
    __shared__ float sB[TC * 16];
    const int tid = threadIdx.x;
    const int c = blockIdx.x;
    const int dcat = blockIdx.y * 256 + tid;
    const int dir = blockIdx.y >> 3;
    const int dloc = dcat & 2047;
    const int t0 = c * TC;
    const float* dbcD = dbc + (size_t)dir * LS96;
    for (int i = tid; i < TC * 16; i += 256)
        sB[i] = dbcD[(t0 + (i >> 4)) * DBC_LD + DTRANK + (i & 15)];
    __syncthreads();
    const float* Alog = (dir ? A1 : A0) + (size_t)dloc * 16;
    float A[16], h[16], Pa[16];
    #pragma unroll
    for (int n = 0; n < 16; n += 4) {
        const float4 av = *(const float4*)(Alog + n);
        A[n]   = -__expf(av.x); A[n+1] = -__expf(av.y);
        A[n+2] = -__expf(av.z); A[n+3] = -__expf(av.w);
    }
    #pragma unroll
    for (int n = 0; n < 16; ++n) { h[n] = 0.f; Pa[n] = 1.f; }
    #pragma unroll 2
    for (int t = 0; t < TC; ++t) {
        const float dtv = (float)dt[(size_t)(t0 + t) * DCAT + dcat];
        const float du  = dtv * (float)u[(size_t)(t0 + t) * DCAT + dcat];
        #pragma unroll
        for (int n = 0; n < 16; ++n) {
            const float a = __expf(dtv * A[n]);
            h[n] = a * h[n] + du * sB[t * 16 + n];
            Pa[n] *= a;
        }
    }
    __bf16* pp = Pb + ((size_t)c * DCAT + dcat) * 16;
    __bf16* sp = Sb + ((size_t)c * DCAT + dcat) * 16;
    bf16x8 pv0, pv1, sv0, sv1;
    #pragma unroll
    for (int n = 0; n < 8; ++n) {
        pv0[n] = (__bf16)Pa[n]; pv1[n] = (__bf16)Pa[n + 8];
        sv0[n] = (__bf16)h[n];  sv1[n] = (__bf16)h[n + 8];
    }
    *(bf16x8*)pp = pv0; *(bf16x8*)(pp + 8) = pv1;
    *(bf16x8*)sp = sv0; *(bf16x8*)(sp + 8) = sv1;
}

// ---------------------------------------------------------------- scan phase 2: combine chunk states
__global__ __launch_bounds__(256) void scan_mid(
    const __bf16* __restrict__ Pb, const __bf16* __restrict__ Sb, __bf16* __restrict__ Hb)
{
    const int i = blockIdx.x * 256 + threadIdx.x;    // (dcat,n) flat, 0..65535
    float H = 0.f;
    for (int c = 0; c < NC; ++c) {
        Hb[(size_t)c * 65536 + i] = (__bf16)H;
        H = (float)Pb[(size_t)c * 65536 + i] * H + (float)Sb[(size_t)c * 65536 + i];
    }
}

// ---------------------------------------------------------------- scan phase 3: recompute + y + gate -> ygcat
__global__ __launch_bounds__(256) void scan_p3(
    const __bf16* __restrict__ u, const __bf16* __restrict__ dt,
    const float* __restrict__ dbc, const float* __restrict__ A0, const float* __restrict__ A1,
    const float* __restrict__ Dp0, const float* __restrict__ Dp1,
    const __bf16* __restrict__ Hb, const __bf16* __restrict__ xz,
    __bf16* __restrict__ ygcat)
{
    __shared__ float sB[TC * 16], sC[TC * 16];
    const int tid = threadIdx.x;
    const int c = blockIdx.x;
    const int dcat = blockIdx.y * 256 + tid;
    const int dir = blockIdx.y >> 3;
    const int dloc = dcat & 2047;
    const int t0 = c * TC;
    const float* dbcD = dbc + (size_t)dir * LS96;
    for (int i = tid; i < TC * 16; i += 256) {
        sB[i] = dbcD[(t0 + (i >> 4)) * DBC_LD + DTRANK + (i & 15)];
        sC[i] = dbcD[(t0 + (i >> 4)) * DBC_LD + DTRANK + DSTATE + (i & 15)];
    }
    __syncthreads();
    const float* Alog = (dir ? A1 : A0) + (size_t)dloc * 16;
    const __bf16* hp = Hb + ((size_t)c * DCAT + dcat) * 16;
    const bf16x8 hv0 = *(const bf16x8*)hp;
    const bf16x8 hv1 = *(const bf16x8*)(hp + 8);
    float A[16], h[16];
    #pragma unroll
    for (int n = 0; n < 8; ++n) { h[n] = (float)hv0[n]; h[n + 8] = (float)hv1[n]; }
    #pragma unroll
    for (int n = 0; n < 16; n += 4) {
        const float4 av = *(const float4*)(Alog + n);
        A[n]   = -__expf(av.x); A[n+1] = -__expf(av.y);
        A[n+2] = -__expf(av.z); A[n+3] = -__expf(av.w);
    }
    const float Dv = (dir ? Dp1 : Dp0)[dloc];
    const __bf16* zsrc = xz + dir * 4096 + 2048 + dloc;
    #pragma unroll 2
    for (int t = 0; t < TC; ++t) {
        const float dtv = (float)dt[(size_t)(t0 + t) * DCAT + dcat];
        const float uv  = (float)u[(size_t)(t0 + t) * DCAT + dcat];
        const float du  = dtv * uv;
        float y = uv * Dv;
        #pragma unroll
        for (int n = 0; n < 16; ++n) {
            const float a = __expf(dtv * A[n]);
            h[n] = a * h[n] + du * sB[t * 16 + n];
            y += h[n] * sC[t * 16 + n];
        }
        const float zv = (float)zsrc[(size_t)(t0 + t) * XZLD];
        const int orow = dir ? (L_SEQ - 1 - (t0 + t)) : (t0 + t);
        ygcat[(size_t)orow * DCAT + dcat] = (__bf16)(y * (zv / (1.f + __expf(-zv))));
    }
}

// ---------------------------------------------------------------- x2 = x + rmsnorm(sum P0..3)*mw ; h2_16
__global__ __launch_bounds__(256) void addnorm2_kernel(
    const float* __restrict__ x0, const float* __restrict__ P,
    const float* __restrict__ mw, const float* __restrict__ w2,
    float* __restrict__ x2, __bf16* __restrict__ h2_16)
{
    __shared__ float sred[8];
    const int row = blockIdx.x, t = threadIdx.x;
    const size_t PS = (size_t)L_SEQ * DMODEL;
    float4 yv = ((const float4*)(P + (size_t)row * DMODEL))[t];
    #pragma unroll
    for (int s = 1; s < 4; ++s) {
        float4 pv = ((const float4*)(P + s * PS + (size_t)row * DMODEL))[t];
        yv.x += pv.x; yv.y += pv.y; yv.z += pv.z; yv.w += pv.w;
    }
    float ss = yv.x*yv.x + yv.y*yv.y + yv.z*yv.z + yv.w*yv.w;
    #pragma unroll
    for (int m = 1; m < 64; m <<= 1) ss += __shfl_xor(ss, m);
    if ((t & 63) == 0) sred[t >> 6] = ss;
    __syncthreads();
    const float s1 = sred[0] + sred[1] + sred[2] + sred[3];
    const float sc1 = rsqrtf(s1 * (1.f / DMODEL) + 1e-6f);
    float4 xv = ((const float4*)(x0 + (size_t)row * DMODEL))[t];
    float4 mv = ((const float4*)mw)[t];
    float4 o;
    o.x = xv.x + mv.x * yv.x * sc1; o.y = xv.y + mv.y * yv.y * sc1;
    o.z = xv.z + mv.z * yv.z * sc1; o.w = xv.w + mv.w * yv.w * sc1;
    ((float4*)(x2 + (size_t)row * DMODEL))[t] = o;
    float s2 = o.x*o.x + o.y*o.y + o.z*o.z + o.w*o.w;
    #pragma unroll
    for (int m = 1; m < 64; m <<= 1) s2 += __shfl_xor(s2, m);
    if ((t & 63) == 0) sred[4 + (t >> 6)] = s2;
    __syncthreads();
    const float st = sred[4] + sred[5] + sred[6] + sred[7];
    const float sc2 = rsqrtf(st * (1.f / DMODEL) + 1e-6f);
    float4 wv = ((const float4*)w2)[t];
    bf16x4 o2;
    o2[0] = (__bf16)(wv.x * o.x * sc2); o2[1] = (__bf16)(wv.y * o.y * sc2);
    o2[2] = (__bf16)(wv.z * o.z * sc2); o2[3] = (__bf16)(wv.w * o.w * sc2);
    *(bf16x4*)&h2_16[(size_t)row * DMODEL + t * 4] = o2;
}

// ---------------------------------------------------------------- d_out = x2 + sum P0..3
__global__ __launch_bounds__(256) void addout_kernel(
    const float* __restrict__ x2, const float* __restrict__ P, float* __restrict__ out)
{
    const size_t i = ((size_t)blockIdx.x * 256 + threadIdx.x) * 4;
    const size_t PS = (size_t)L_SEQ * DMODEL;
    float4 v = *(const float4*)(x2 + i);
    #pragma unroll
    for (int s = 0; s < 4; ++s) {
        const float4 pv = *(const float4*)(P + s * PS + i);
        v.x += pv.x; v.y += pv.y; v.z += pv.z; v.w += pv.w;
    }
    *(float4*)(out + i) = v;
}

// ---------------------------------------------------------------- launch
extern "C" void kernel_launch(void* const* d_in, const int* in_sizes, int n_in,
                              void* d_out, int out_size, void* d_ws, size_t ws_size,
                              hipStream_t stream)
{
    const float* x       = (const float*)d_in[0];
    const float* mask    = (const float*)d_in[1];
    const float* mnorm_w = (const float*)d_in[2];
    const float* ln1_w   = (const float*)d_in[3];
    const float* ln2_w   = (const float*)d_in[4];
    const float* gate_w  = (const float*)d_in[5];
    const float* up_w    = (const float*)d_in[6];
    const float* down_w  = (const float*)d_in[7];
    const float* in_w[2]    = {(const float*)d_in[8],  (const float*)d_in[17]};
    const float* conv_w[2]  = {(const float*)d_in[9],  (const float*)d_in[18]};
    const float* conv_b[2]  = {(const float*)d_in[10], (const float*)d_in[19]};
    const float* xproj_w[2] = {(const float*)d_in[11], (const float*)d_in[20]};
    const float* dt_w[2]    = {(const float*)d_in[12], (const float*)d_in[21]};
    const float* dt_b[2]    = {(const float*)d_in[13], (const float*)d_in[22]};
    const float* A_log[2]   = {(const float*)d_in[14], (const float*)d_in[23]};
    const float* Dp[2]      = {(const float*)d_in[15], (const float*)d_in[24]};
    const float* out_w[2]   = {(const float*)d_in[16], (const float*)d_in[25]};

    float* ws = (float*)d_ws;
    const size_t MF = 1u << 20;   // 1M floats = 4MB
    __bf16* h16    = (__bf16*)(ws);                    // [0,1)
    float*  x2     = ws + 1 * MF;                      // [1,3)
    __bf16* xzcat  = (__bf16*)(ws + 3 * MF);           // [3,11)   L x 8192 bf16
    __bf16* xc16   = (__bf16*)(ws + 11 * MF);          // [11,15)  L x 4096 bf16
    __bf16* dtb16  = (__bf16*)(ws + 15 * MF);          // [15,19)  L x 4096 bf16
    float*  dbc    = ws + 19 * MF;                     // [19,20): 2 x L x 96 f32 + dbc16
    __bf16* dbc16  = (__bf16*)(ws + 19 * MF + 393216); // 2 x L x 64 bf16
    float*  dbcP   = ws + 20 * MF;                     // [20,24): 16 x L x 96 f32
    __bf16* Pb     = (__bf16*)(ws + 24 * MF);          // [24,26)
    __bf16* Sb     = (__bf16*)(ws + 26 * MF);          // [26,28)
    __bf16* Hb     = (__bf16*)(ws + 28 * MF);          // [28,30)
    float*  gemmP  = ws + 20 * MF;                     // [20,28) alias (dbcP/Pb/Sb dead by then)
    __bf16* ygcat  = (__bf16*)(ws + 30 * MF);          // [30,34)
    __bf16* h2_16  = (__bf16*)(ws + 34 * MF);          // [34,35)
    __bf16* wbase  = (__bf16*)(ws + 35 * MF);
    const size_t M4 = 4u << 20;
    __bf16* wINcat  = wbase;                           // 8192 x 1024
    __bf16* wOUTcat = wbase + 2 * M4;                  // 1024 x 4096
    __bf16* wG      = wbase + 3 * M4;
    __bf16* wU      = wbase + 4 * M4;
    __bf16* wDN     = wbase + 5 * M4;
    __bf16* wXP[2]  = {wbase + 6 * M4,            wbase + 6 * M4 + 196608};
    __bf16* wDT[2]  = {wbase + 6 * M4 + 393216,   wbase + 6 * M4 + 524288};
    __bf16* mbuf16  = ygcat;

    // ---- weight conversion
    CvtJobs j;
    const float* srcs[NJOBS] = {in_w[0], in_w[1], gate_w, up_w, down_w,
                                xproj_w[0], xproj_w[1], dt_w[0], dt_w[1]};
    __bf16* dsts[NJOBS] = {wINcat, wINcat + M4, wG, wU, wDN, wXP[0], wXP[1], wDT[0], wDT[1]};
    const int szs[NJOBS] = {4194304, 4194304, 4194304, 4194304, 4194304,
                            196608, 196608, 131072, 131072};
    int cum = 0;
    for (int i = 0; i < NJOBS; ++i) {
        j.src[i] = srcs[i]; j.dst[i] = dsts[i]; j.cum[i] = cum; cum += szs[i] / 8;
    }
    j.cum[NJOBS] = cum;
    cvt_multi<<<(cum + 255) / 256, 256, 0, stream>>>(j, cum);
    cvt_outw<<<(2 * 1024 * 2048 / 8) / 256, 256, 0, stream>>>(out_w[0], out_w[1], wOUTcat);

    rmsnorm_mask_kernel<<<L_SEQ, 256, 0, stream>>>(x, ln1_w, mask, h16);

    // fused bidirectional in-proj -> xzcat (bf16, b-half rows flipped)
    k_inproj<<<dim3(16, 64), 256, 0, stream>>>(
        h16, wINcat, xzcat, 2048, 8192, 1024, 1024, 1024, 8192);

    // conv + silu over both dirs -> xc16
    conv_silu_kernel<<<(L_SEQ * DCAT) / 256, 256, 0, stream>>>(
        xzcat, conv_w[0], conv_b[0], conv_w[1], conv_b[1], xc16);

    // xproj partials, both dirs + K-split in one dispatch
    k_xproj<<<dim3(16, 1, 16), 256, 0, stream>>>(xc16, wXP[0], wXP[1], dbcP);
    dbc_finalize<<<(2 * LS96) / 256, 256, 0, stream>>>(dbcP, dbc, dbc16);

    // dt = softplus(dt_raw @ dt_w^T + dt_b), both dirs -> dtb16
    k_dt<<<dim3(16, 16, 2), 256, 0, stream>>>(
        dbc16, wDT[0], wDT[1], dt_b[0], dt_b[1], dtb16);

    // chunk-parallel selective scan over both dirs -> ygcat
    scan_p1<<<dim3(NC, 16), 256, 0, stream>>>(
        xc16, dtb16, dbc, A_log[0], A_log[1], Pb, Sb);
    scan_mid<<<65536 / 256, 256, 0, stream>>>(Pb, Sb, Hb);
    scan_p3<<<dim3(NC, 16), 256, 0, stream>>>(
        xc16, dtb16, dbc, A_log[0], A_log[1], Dp[0], Dp[1], Hb, xzcat, ygcat);

    // fused out-proj partials (K=4096 split 4)
    k_partial<<<dim3(16, 8, 4), 256, 0, stream>>>(
        ygcat, wOUTcat, gemmP, 2048, 1024, 4096, 4096, 4096, 1024, 4);
    addnorm2_kernel<<<L_SEQ, 256, 0, stream>>>(x, gemmP, mnorm_w, ln2_w, x2, h2_16);

    // MLP
    gemm_mlp<<<dim3(16, 64), 256, 0, stream>>>(
        h2_16, wG, wU, mbuf16, 2048, 4096, 1024, 1024, 1024, 4096);
    k_partial<<<dim3(16, 8, 4), 256, 0, stream>>>(
        mbuf16, wDN, gemmP, 2048, 1024, 4096, 4096, 4096, 1024, 4);
    addout_kernel<<<(L_SEQ * DMODEL) / (256 * 4), 256, 0, stream>>>(
        x2, gemmP, (float*)d_out);
}